// Round 1
// baseline (726.181 us; speedup 1.0000x reference)
//
#include <hip/hip_runtime.h>
#include <hip/hip_bf16.h>

#define NH    12
#define HD    64
#define NTOK  1024
#define BATCH 8
#define DM    768

// ---------------------------------------------------------------------------
// Kernel 1: v[b,h,n,j] = sum_k query[n,b,k] * w_v[h*64+j, k]
// Fused epilogue: rnorm[b,h,n] = rsqrt(sum_j v^2)   (head dim == tile width)
// 64x64 C-tile, K-tile 32, 256 threads, 4x4 micro-tile per thread.
// ---------------------------------------------------------------------------
__global__ __launch_bounds__(256) void vproj_kernel(
    const float* __restrict__ q, const float* __restrict__ w,
    float* __restrict__ v_ws, float* __restrict__ rn_ws)
{
    __shared__ float As[32][65];   // [k][m] transposed
    __shared__ float Bs[32][65];   // [k][d]
    const int h   = blockIdx.x;    // head (N-block of 64 cols == one head)
    const int mb  = blockIdx.y;    // 0..127 row-block over B*N
    const int tid = threadIdx.x;
    const int tx  = tid & 15, ty = tid >> 4;
    const int m0  = mb * 64;
    const int b   = m0 >> 10;      // 64 | 1024, so one batch per block
    const int lk  = tid & 31;
    const int lr  = tid >> 5;

    float acc[4][4] = {};

    for (int kt = 0; kt < DM; kt += 32) {
        #pragma unroll
        for (int p = 0; p < 8; ++p) {
            int row = lr + p * 8;                    // 0..63
            int n   = (m0 + row) & (NTOK - 1);
            As[lk][row] = q[(size_t)(n * BATCH + b) * DM + kt + lk];
            Bs[lk][row] = w[(size_t)(h * HD + row) * DM + kt + lk];
        }
        __syncthreads();
        #pragma unroll 8
        for (int k = 0; k < 32; ++k) {
            float a0 = As[k][4*ty+0], a1 = As[k][4*ty+1];
            float a2 = As[k][4*ty+2], a3 = As[k][4*ty+3];
            float b0 = Bs[k][4*tx+0], b1 = Bs[k][4*tx+1];
            float b2 = Bs[k][4*tx+2], b3 = Bs[k][4*tx+3];
            acc[0][0] += a0*b0; acc[0][1] += a0*b1; acc[0][2] += a0*b2; acc[0][3] += a0*b3;
            acc[1][0] += a1*b0; acc[1][1] += a1*b1; acc[1][2] += a1*b2; acc[1][3] += a1*b3;
            acc[2][0] += a2*b0; acc[2][1] += a2*b1; acc[2][2] += a2*b2; acc[2][3] += a2*b3;
            acc[3][0] += a3*b0; acc[3][1] += a3*b1; acc[3][2] += a3*b2; acc[3][3] += a3*b3;
        }
        __syncthreads();
    }

    const int bh = b * NH + h;
    #pragma unroll
    for (int i = 0; i < 4; ++i) {
        float ss = acc[i][0]*acc[i][0] + acc[i][1]*acc[i][1]
                 + acc[i][2]*acc[i][2] + acc[i][3]*acc[i][3];
        #pragma unroll
        for (int msk = 1; msk < 16; msk <<= 1)
            ss += __shfl_xor(ss, msk, 16);           // row-group = 16 contiguous lanes
        int row = 4*ty + i;
        int n   = (m0 + row) & (NTOK - 1);
        float4 val = make_float4(acc[i][0], acc[i][1], acc[i][2], acc[i][3]);
        *(float4*)&v_ws[((size_t)bh * NTOK + n) * HD + 4*tx] = val;
        if (tx == 0) rn_ws[(size_t)bh * NTOK + n] = rsqrtf(ss);
    }
}

// ---------------------------------------------------------------------------
// Kernel 2: flash attention per (b,h). Q-tile 64 rows, K-tiles of 64.
// Q normalized * scale in LDS; K normalized; V raw. P reuses the K buffer.
// 256 threads, 4x4 micro-tile, online softmax via 16-lane shuffles.
// LDS: 3 * 64*65*4 = 49.9 KB  -> 3 blocks/CU.
// ---------------------------------------------------------------------------
__global__ __launch_bounds__(256) void attn_kernel(
    const float* __restrict__ v_ws, const float* __restrict__ rn_ws,
    float* __restrict__ out)
{
    __shared__ float Qs[64][65];
    __shared__ float Ks[64][65];   // reused as P after S-compute
    __shared__ float Vs[64][65];
    const int bh  = blockIdx.y;
    const int q0  = blockIdx.x * 64;
    const int tid = threadIdx.x;
    const int tx  = tid & 15, ty = tid >> 4;
    const float* vb = v_ws + (size_t)bh * NTOK * HD;
    const float* rb = rn_ws + (size_t)bh * NTOK;

    {   // load Q tile, normalized, scale folded in
        int r  = tid >> 4;
        int j4 = (tid & 15) * 4;
        #pragma unroll
        for (int p = 0; p < 64; p += 16) {
            int row = r + p;
            float rn = rb[q0 + row] * 0.125f;        // scale = hd^-0.5
            float4 val = *(const float4*)&vb[(size_t)(q0 + row) * HD + j4];
            Qs[row][j4+0] = val.x * rn;
            Qs[row][j4+1] = val.y * rn;
            Qs[row][j4+2] = val.z * rn;
            Qs[row][j4+3] = val.w * rn;
        }
    }

    float m_run[4], l_run[4], o[4][4] = {};
    #pragma unroll
    for (int i = 0; i < 4; ++i) { m_run[i] = -1e30f; l_run[i] = 0.f; }

    for (int kt = 0; kt < NTOK / 64; ++kt) {
        __syncthreads();                              // prev PV done (also covers Q load)
        {
            int r  = tid >> 4;
            int j4 = (tid & 15) * 4;
            #pragma unroll
            for (int p = 0; p < 64; p += 16) {
                int row = r + p;
                int g   = kt * 64 + row;
                float rn = rb[g];
                float4 val = *(const float4*)&vb[(size_t)g * HD + j4];
                Ks[row][j4+0] = val.x * rn;
                Ks[row][j4+1] = val.y * rn;
                Ks[row][j4+2] = val.z * rn;
                Ks[row][j4+3] = val.w * rn;
                Vs[row][j4+0] = val.x;
                Vs[row][j4+1] = val.y;
                Vs[row][j4+2] = val.z;
                Vs[row][j4+3] = val.w;
            }
        }
        __syncthreads();

        // S = Qn * Kn^T  (scale already folded into Q)
        float s[4][4] = {};
        #pragma unroll 8
        for (int k = 0; k < HD; ++k) {
            float a0 = Qs[4*ty+0][k], a1 = Qs[4*ty+1][k];
            float a2 = Qs[4*ty+2][k], a3 = Qs[4*ty+3][k];
            float b0 = Ks[4*tx+0][k], b1 = Ks[4*tx+1][k];
            float b2 = Ks[4*tx+2][k], b3 = Ks[4*tx+3][k];
            s[0][0] += a0*b0; s[0][1] += a0*b1; s[0][2] += a0*b2; s[0][3] += a0*b3;
            s[1][0] += a1*b0; s[1][1] += a1*b1; s[1][2] += a1*b2; s[1][3] += a1*b3;
            s[2][0] += a2*b0; s[2][1] += a2*b1; s[2][2] += a2*b2; s[2][3] += a2*b3;
            s[3][0] += a3*b0; s[3][1] += a3*b1; s[3][2] += a3*b2; s[3][3] += a3*b3;
        }

        // online softmax (per row, all 16 lanes of a row-group hold the result)
        #pragma unroll
        for (int i = 0; i < 4; ++i) {
            float mx = fmaxf(fmaxf(s[i][0], s[i][1]), fmaxf(s[i][2], s[i][3]));
            #pragma unroll
            for (int msk = 1; msk < 16; msk <<= 1)
                mx = fmaxf(mx, __shfl_xor(mx, msk, 16));
            float mnew = fmaxf(m_run[i], mx);
            float al   = __expf(m_run[i] - mnew);     // first tile: exp(-inf)=0
            float ls = 0.f;
            #pragma unroll
            for (int j = 0; j < 4; ++j) { s[i][j] = __expf(s[i][j] - mnew); ls += s[i][j]; }
            #pragma unroll
            for (int msk = 1; msk < 16; msk <<= 1)
                ls += __shfl_xor(ls, msk, 16);
            l_run[i] = l_run[i] * al + ls;
            m_run[i] = mnew;
            #pragma unroll
            for (int j = 0; j < 4; ++j) o[i][j] *= al;
        }

        __syncthreads();                              // all done reading Ks
        #pragma unroll
        for (int i = 0; i < 4; ++i)
            #pragma unroll
            for (int j = 0; j < 4; ++j)
                Ks[4*ty+i][4*tx+j] = s[i][j];         // P overwrites K buffer
        __syncthreads();

        // O += P @ V
        #pragma unroll 8
        for (int m = 0; m < 64; ++m) {
            float p0 = Ks[4*ty+0][m], p1 = Ks[4*ty+1][m];
            float p2 = Ks[4*ty+2][m], p3 = Ks[4*ty+3][m];
            float v0 = Vs[m][4*tx+0], v1 = Vs[m][4*tx+1];
            float v2 = Vs[m][4*tx+2], v3 = Vs[m][4*tx+3];
            o[0][0] += p0*v0; o[0][1] += p0*v1; o[0][2] += p0*v2; o[0][3] += p0*v3;
            o[1][0] += p1*v0; o[1][1] += p1*v1; o[1][2] += p1*v2; o[1][3] += p1*v3;
            o[2][0] += p2*v0; o[2][1] += p2*v1; o[2][2] += p2*v2; o[2][3] += p2*v3;
            o[3][0] += p3*v0; o[3][1] += p3*v1; o[3][2] += p3*v2; o[3][3] += p3*v3;
        }
    }

    const int b = bh / NH, h = bh % NH;
    #pragma unroll
    for (int i = 0; i < 4; ++i) {
        int row = q0 + 4*ty + i;
        float inv = 1.f / l_run[i];
        float4 val = make_float4(o[i][0]*inv, o[i][1]*inv, o[i][2]*inv, o[i][3]*inv);
        *(float4*)&out[(size_t)row * (BATCH*DM) + b*DM + h*HD + 4*tx] = val;
    }
}

extern "C" void kernel_launch(void* const* d_in, const int* in_sizes, int n_in,
                              void* d_out, int out_size, void* d_ws, size_t ws_size,
                              hipStream_t stream) {
    const float* q = (const float*)d_in[0];   // [1024, 8, 768]
    const float* w = (const float*)d_in[1];   // [768, 768]
    float* out  = (float*)d_out;              // [1024, 8, 768]
    float* v_ws = (float*)d_ws;                               // [96][1024][64]
    float* rn_ws = v_ws + (size_t)NH * BATCH * NTOK * HD;     // [96][1024]

    vproj_kernel<<<dim3(NH, (BATCH * NTOK) / 64), 256, 0, stream>>>(q, w, v_ws, rn_ws);
    attn_kernel<<<dim3(NTOK / 64, BATCH * NH), 256, 0, stream>>>(v_ws, rn_ws, out);
}

// Round 2
// 279.546 us; speedup vs baseline: 2.5977x; 2.5977x over previous
//
#include <hip/hip_runtime.h>
#include <hip/hip_bf16.h>

#define NH    12
#define HD    64
#define NTOK  1024
#define BATCH 8
#define DM    768

typedef short short8 __attribute__((ext_vector_type(8)));
typedef float f32x4  __attribute__((ext_vector_type(4)));

__device__ __forceinline__ ushort f2bf(float f) {
    union { float f; unsigned u; } x; x.f = f;
    unsigned r = x.u + 0x7FFF + ((x.u >> 16) & 1);   // RNE
    return (ushort)(r >> 16);
}

// ---------------------------------------------------------------------------
// Kernel 1: fp32 GEMM v = q @ w^T per (head, 64-row block).
// Epilogue: vn[bh][n][64] = bf16(v * rsqrt(sum v^2))   (Q/K operand)
//           vt[bh][d][n]  = bf16(v) transposed          (V operand for PV)
// ---------------------------------------------------------------------------
__global__ __launch_bounds__(256) void vproj_kernel(
    const float* __restrict__ q, const float* __restrict__ w,
    ushort* __restrict__ vn, ushort* __restrict__ vt)
{
    __shared__ __align__(16) char smem[2 * 32 * 65 * 4];
    float (*As)[65] = (float (*)[65])smem;                 // [k][m]
    float (*Bs)[65] = (float (*)[65])(smem + 32 * 65 * 4); // [k][d]
    const int h   = blockIdx.x;
    const int mb  = blockIdx.y;
    const int tid = threadIdx.x;
    const int tx  = tid & 15, ty = tid >> 4;
    const int m0  = mb * 64;
    const int b   = m0 >> 10;
    const int lk  = tid & 31;
    const int lr  = tid >> 5;

    float acc[4][4] = {};

    for (int kt = 0; kt < DM; kt += 32) {
        #pragma unroll
        for (int p = 0; p < 8; ++p) {
            int row = lr + p * 8;
            int n   = (m0 + row) & (NTOK - 1);
            As[lk][row] = q[(size_t)(n * BATCH + b) * DM + kt + lk];
            Bs[lk][row] = w[(size_t)(h * HD + row) * DM + kt + lk];
        }
        __syncthreads();
        #pragma unroll 8
        for (int k = 0; k < 32; ++k) {
            float a0 = As[k][4*ty+0], a1 = As[k][4*ty+1];
            float a2 = As[k][4*ty+2], a3 = As[k][4*ty+3];
            float b0 = Bs[k][4*tx+0], b1 = Bs[k][4*tx+1];
            float b2 = Bs[k][4*tx+2], b3 = Bs[k][4*tx+3];
            acc[0][0] += a0*b0; acc[0][1] += a0*b1; acc[0][2] += a0*b2; acc[0][3] += a0*b3;
            acc[1][0] += a1*b0; acc[1][1] += a1*b1; acc[1][2] += a1*b2; acc[1][3] += a1*b3;
            acc[2][0] += a2*b0; acc[2][1] += a2*b1; acc[2][2] += a2*b2; acc[2][3] += a2*b3;
            acc[3][0] += a3*b0; acc[3][1] += a3*b1; acc[3][2] += a3*b2; acc[3][3] += a3*b3;
        }
        __syncthreads();
    }

    const int bh = b * NH + h;
    const int n0 = m0 & (NTOK - 1);

    // vn = normalized bf16
    #pragma unroll
    for (int i = 0; i < 4; ++i) {
        float ss = acc[i][0]*acc[i][0] + acc[i][1]*acc[i][1]
                 + acc[i][2]*acc[i][2] + acc[i][3]*acc[i][3];
        #pragma unroll
        for (int msk = 1; msk < 16; msk <<= 1)
            ss += __shfl_xor(ss, msk, 16);
        float rn = rsqrtf(ss);
        int n = n0 + 4*ty + i;
        ushort4 o;
        o.x = f2bf(acc[i][0] * rn); o.y = f2bf(acc[i][1] * rn);
        o.z = f2bf(acc[i][2] * rn); o.w = f2bf(acc[i][3] * rn);
        *(ushort4*)&vn[((size_t)bh * NTOK + n) * HD + 4*tx] = o;
    }

    // vt = raw v transposed, via LDS bounce (reuse smem)
    ushort (*T)[72] = (ushort (*)[72])smem;   // 64 x 72 bf16 = 9216 B
    #pragma unroll
    for (int i = 0; i < 4; ++i)
        #pragma unroll
        for (int j = 0; j < 4; ++j)
            T[4*tx + j][4*ty + i] = f2bf(acc[i][j]);
    __syncthreads();
    {
        int d = tid >> 2, c = tid & 3;
        uint4 lo = *(const uint4*)&T[d][c*16];
        uint4 hi = *(const uint4*)&T[d][c*16 + 8];
        size_t go = ((size_t)bh * HD + d) * NTOK + n0 + c*16;
        *(uint4*)&vt[go]     = lo;
        *(uint4*)&vt[go + 8] = hi;
    }
}

// ---------------------------------------------------------------------------
// Kernel 2: flash attention, bf16 MFMA (16x16x32), fp32 softmax.
// 4 waves; wave w owns q-rows [q0+16w, q0+16w+16). KV tiles of 64.
// K tile [kv][64] and Vt tile [dim][kv] in LDS, XOR-swizzled 16B chunks.
// P through per-wave LDS (layout change D-frag -> A-frag), also swizzled.
// ---------------------------------------------------------------------------
__global__ __launch_bounds__(256) void attn_kernel(
    const ushort* __restrict__ vn, const ushort* __restrict__ vt,
    float* __restrict__ out)
{
    __shared__ __align__(16) ushort Klds[64 * 64];     // [kv][dim], swizzled
    __shared__ __align__(16) ushort Vlds[64 * 64];     // [dim][kv], swizzled
    __shared__ __align__(16) ushort Plds[4 * 16 * 64]; // per-wave [q][kv], swizzled
    const int bh  = blockIdx.y;
    const int q0  = blockIdx.x * 64;
    const int tid = threadIdx.x;
    const int wv  = tid >> 6;
    const int l   = tid & 63;
    const int rl  = l & 15, lg = l >> 4;

    const ushort* vb  = vn + (size_t)bh * NTOK * HD;
    const ushort* vtb = vt + (size_t)bh * HD * NTOK;
    ushort* Pw = Plds + wv * 16 * 64;

    // Q A-frags: A[m=q][k=dim], lane holds A[l&15][(l>>4)*8 + j] (+32 for f=1)
    short8 qf[2];
    {
        int qrow = q0 + wv*16 + rl;
        qf[0] = *(const short8*)(vb + (size_t)qrow * HD + lg*8);
        qf[1] = *(const short8*)(vb + (size_t)qrow * HD + 32 + lg*8);
    }

    f32x4 o_acc[4] = {};
    float m_run[4], l_run[4];
    #pragma unroll
    for (int i = 0; i < 4; ++i) { m_run[i] = -1e30f; l_run[i] = 0.f; }

    for (int kt = 0; kt < NTOK / 64; ++kt) {
        __syncthreads();                       // prev tile's LDS reads done
        // stage K (normalized) and Vt (raw, [dim][kv]) — swizzled writes
        #pragma unroll
        for (int rnd = 0; rnd < 2; ++rnd) {
            int chunk = rnd * 256 + tid;       // 0..511 16B chunks
            int r = chunk >> 3, c = chunk & 7;
            int slot = c ^ (r & 7);
            uint4 kk = *(const uint4*)(vb + (size_t)(kt*64 + r) * HD + c*8);
            *(uint4*)(Klds + r*64 + slot*8) = kk;
            uint4 vv = *(const uint4*)(vtb + (size_t)r * NTOK + kt*64 + c*8);
            *(uint4*)(Vlds + r*64 + slot*8) = vv;
        }
        __syncthreads();

        // S = Q . Kn^T : B[k=dim][n=kv], lane holds Kn[g*16+(l&15)][f*32+(l>>4)*8+j]
        f32x4 s[4] = {};
        #pragma unroll
        for (int g = 0; g < 4; ++g) {
            int r = g*16 + rl;
            #pragma unroll
            for (int f = 0; f < 2; ++f) {
                int cc = f*4 + lg;
                short8 bk = *(const short8*)(Klds + r*64 + ((cc ^ (r & 7)) * 8));
                s[g] = __builtin_amdgcn_mfma_f32_16x16x32_bf16(qf[f], bk, s[g], 0, 0, 0);
            }
        }

        // online softmax, fp32. Row r = lg*4+i held by the 16 lanes of group lg.
        ushort pb[4][4];
        #pragma unroll
        for (int i = 0; i < 4; ++i) {
            float mx = -1e30f;
            #pragma unroll
            for (int g = 0; g < 4; ++g) { s[g][i] *= 0.125f; mx = fmaxf(mx, s[g][i]); }
            #pragma unroll
            for (int msk = 1; msk < 16; msk <<= 1)
                mx = fmaxf(mx, __shfl_xor(mx, msk, 16));
            float mnew = fmaxf(m_run[i], mx);
            float al   = __expf(m_run[i] - mnew);
            float ls = 0.f;
            #pragma unroll
            for (int g = 0; g < 4; ++g) {
                float p = __expf(s[g][i] - mnew);
                s[g][i] = p; ls += p;
            }
            #pragma unroll
            for (int msk = 1; msk < 16; msk <<= 1)
                ls += __shfl_xor(ls, msk, 16);
            l_run[i] = l_run[i] * al + ls;
            m_run[i] = mnew;
            #pragma unroll
            for (int dg = 0; dg < 4; ++dg) o_acc[dg][i] *= al;
            #pragma unroll
            for (int g = 0; g < 4; ++g) pb[g][i] = f2bf(s[g][i]);
        }

        // write P to wave-local LDS (D-frag layout), swizzled
        #pragma unroll
        for (int g = 0; g < 4; ++g)
            #pragma unroll
            for (int i = 0; i < 4; ++i) {
                int row = lg*4 + i;
                int byr = (g*16 + rl) * 2;
                *(ushort*)((char*)Pw + row*128 + (byr ^ ((row & 7) << 4))) = pb[g][i];
            }

        // O += P @ V : A from Plds, B from Vlds (wave-local P, no barrier)
        #pragma unroll
        for (int kvg = 0; kvg < 2; ++kvg) {
            int pcc = kvg*4 + lg;
            short8 pa = *(const short8*)((const char*)Pw + rl*128 + ((pcc ^ (rl & 7)) * 16));
            #pragma unroll
            for (int dg = 0; dg < 4; ++dg) {
                int vr = dg*16 + rl;
                int vcc = kvg*4 + lg;
                short8 bv = *(const short8*)(Vlds + vr*64 + ((vcc ^ (vr & 7)) * 8));
                o_acc[dg] = __builtin_amdgcn_mfma_f32_16x16x32_bf16(pa, bv, o_acc[dg], 0, 0, 0);
            }
        }
    }

    // epilogue: out[n][b][h*64+d] = o / l
    const int b = bh / NH, h = bh % NH;
    #pragma unroll
    for (int i = 0; i < 4; ++i) {
        int n = q0 + wv*16 + lg*4 + i;
        float inv = 1.f / l_run[i];
        #pragma unroll
        for (int dg = 0; dg < 4; ++dg)
            out[((size_t)n * BATCH + b) * DM + h*HD + dg*16 + rl] = o_acc[dg][i] * inv;
    }
}

extern "C" void kernel_launch(void* const* d_in, const int* in_sizes, int n_in,
                              void* d_out, int out_size, void* d_ws, size_t ws_size,
                              hipStream_t stream) {
    const float* q = (const float*)d_in[0];   // [1024, 8, 768]
    const float* w = (const float*)d_in[1];   // [768, 768]
    float* out = (float*)d_out;               // [1024, 8, 768]
    ushort* vn = (ushort*)d_ws;                              // [96][1024][64] bf16
    ushort* vt = vn + (size_t)NH * BATCH * NTOK * HD;        // [96][64][1024] bf16

    vproj_kernel<<<dim3(NH, (BATCH * NTOK) / 64), 256, 0, stream>>>(q, w, vn, vt);
    attn_kernel<<<dim3(NTOK / 64, BATCH * NH), 256, 0, stream>>>(vn, vt, out);
}

// Round 4
// 146.693 us; speedup vs baseline: 4.9503x; 1.9057x over previous
//
#include <hip/hip_runtime.h>
#include <hip/hip_bf16.h>

#define NH    12
#define HD    64
#define NTOK  1024
#define BATCH 8
#define DM    768

typedef short  short8  __attribute__((ext_vector_type(8)));
typedef float  f32x4   __attribute__((ext_vector_type(4)));
typedef unsigned short ushort8 __attribute__((ext_vector_type(8)));

__device__ __forceinline__ ushort f2bf(float f) {
    union { float f; unsigned u; } x; x.f = f;
    unsigned r = x.u + 0x7FFF + ((x.u >> 16) & 1);   // RNE
    return (ushort)(r >> 16);
}
__device__ __forceinline__ float bf2f(ushort h) {
    union { unsigned u; float f; } x; x.u = ((unsigned)h) << 16;
    return x.f;
}
__device__ __forceinline__ void gl_lds16(const ushort* g, ushort* l) {
    __builtin_amdgcn_global_load_lds(
        (const __attribute__((address_space(1))) unsigned int*)g,
        (__attribute__((address_space(3))) unsigned int*)l, 16, 0, 0);
}

// ---------------------------------------------------------------------------
// Split kernels: x -> (hi, lo) bf16 with hi = bf16(x), lo = bf16(x - hi).
// q is also transposed [n][b][d] -> [b][n][d] so GEMM tile rows are contiguous.
// ---------------------------------------------------------------------------
__global__ __launch_bounds__(256) void split_q_kernel(
    const float* __restrict__ src, ushort* __restrict__ hi, ushort* __restrict__ lo)
{
    int t = blockIdx.x * 256 + threadIdx.x;       // 786432 threads, 8 elems each
    int dblk = t % 96; int nb = t / 96; int b = nb & 7; int n = nb >> 3;
    const float* s = src + (size_t)t * 8;
    size_t o = ((size_t)(b * 1024 + n) * 96 + dblk) * 8;
    float4 x0 = *(const float4*)s, x1 = *(const float4*)(s + 4);
    float xs[8] = {x0.x, x0.y, x0.z, x0.w, x1.x, x1.y, x1.z, x1.w};
    ushort8 h8, l8;
    #pragma unroll
    for (int j = 0; j < 8; ++j) {
        ushort h = f2bf(xs[j]);
        h8[j] = h;
        l8[j] = f2bf(xs[j] - bf2f(h));
    }
    *(ushort8*)(hi + o) = h8;
    *(ushort8*)(lo + o) = l8;
}

__global__ __launch_bounds__(256) void split_w_kernel(
    const float* __restrict__ src, ushort* __restrict__ hi, ushort* __restrict__ lo)
{
    int t = blockIdx.x * 256 + threadIdx.x;       // 73728 threads
    const float* s = src + (size_t)t * 8;
    float4 x0 = *(const float4*)s, x1 = *(const float4*)(s + 4);
    float xs[8] = {x0.x, x0.y, x0.z, x0.w, x1.x, x1.y, x1.z, x1.w};
    ushort8 h8, l8;
    #pragma unroll
    for (int j = 0; j < 8; ++j) {
        ushort h = f2bf(xs[j]);
        h8[j] = h;
        l8[j] = f2bf(xs[j] - bf2f(h));
    }
    size_t o = (size_t)t * 8;
    *(ushort8*)(hi + o) = h8;
    *(ushort8*)(lo + o) = l8;
}

// ---------------------------------------------------------------------------
// vproj via split-bf16 MFMA: C = Ah.Bh + Ah.Bl + Al.Bh  (fp32 accum).
// 64x64 tile per (head h, 64-row block mb), BK=64, 4 waves in 2x2.
// Staging: global_load_lds w16, pre-swizzled global source, swizzled ds_read.
// Epilogue: LDS C-tile -> per-row norm -> vn (normalized bf16), vt (V^T bf16).
// ---------------------------------------------------------------------------
__global__ __launch_bounds__(256) void vproj_mfma_kernel(
    const ushort* __restrict__ qh, const ushort* __restrict__ ql,
    const ushort* __restrict__ wh, const ushort* __restrict__ wl,
    ushort* __restrict__ vn, ushort* __restrict__ vt)
{
    __shared__ __align__(16) char smem[32768];
    ushort* Ah = (ushort*)smem;
    ushort* Al = (ushort*)(smem + 8192);
    ushort* Bh = (ushort*)(smem + 16384);
    ushort* Bl = (ushort*)(smem + 24576);
    const int h   = blockIdx.x, mb = blockIdx.y;
    const int tid = threadIdx.x, wv = tid >> 6, l = tid & 63;
    const int rl  = l & 15, lg = l >> 4;
    const int wm  = wv >> 1, wn = wv & 1;
    const int b   = mb >> 4, n0 = (mb & 15) * 64;

    // per-wave staging tile
    const ushort* gsrc; ushort* ltile; size_t srow0;
    if (wv == 0)      { gsrc = qh; ltile = Ah; srow0 = (size_t)(b * 1024 + n0); }
    else if (wv == 1) { gsrc = ql; ltile = Al; srow0 = (size_t)(b * 1024 + n0); }
    else if (wv == 2) { gsrc = wh; ltile = Bh; srow0 = (size_t)(h * 64); }
    else              { gsrc = wl; ltile = Bl; srow0 = (size_t)(h * 64); }

    f32x4 acc[2][2] = {};

    for (int kt = 0; kt < 12; ++kt) {
        __syncthreads();                              // prev iter's ds_reads done
        #pragma unroll
        for (int p = 0; p < 8; ++p) {
            int r = p * 8 + (l >> 3);
            int c = (l & 7) ^ (r & 7);                // inverse-swizzled source
            gl_lds16(gsrc + (srow0 + r) * 768 + kt * 64 + c * 8,
                     ltile + p * 512);                // linear LDS dest
        }
        __syncthreads();                              // vmcnt(0) drained here

        short8 afh[2][2], afl[2][2], bfh[2][2], bfl[2][2];  // [mi/ni][kh]
        #pragma unroll
        for (int mi = 0; mi < 2; ++mi)
            #pragma unroll
            for (int kh = 0; kh < 2; ++kh) {
                int cc = kh * 4 + lg;
                int ra = wm * 32 + mi * 16 + rl;
                int sa = (cc ^ (ra & 7)) * 8;
                afh[mi][kh] = *(const short8*)(Ah + ra * 64 + sa);
                afl[mi][kh] = *(const short8*)(Al + ra * 64 + sa);
                int rb = wn * 32 + mi * 16 + rl;
                int sb = (cc ^ (rb & 7)) * 8;
                bfh[mi][kh] = *(const short8*)(Bh + rb * 64 + sb);
                bfl[mi][kh] = *(const short8*)(Bl + rb * 64 + sb);
            }
        #pragma unroll
        for (int mi = 0; mi < 2; ++mi)
            #pragma unroll
            for (int ni = 0; ni < 2; ++ni)
                #pragma unroll
                for (int kh = 0; kh < 2; ++kh) {
                    acc[mi][ni] = __builtin_amdgcn_mfma_f32_16x16x32_bf16(
                        afh[mi][kh], bfh[ni][kh], acc[mi][ni], 0, 0, 0);
                    acc[mi][ni] = __builtin_amdgcn_mfma_f32_16x16x32_bf16(
                        afh[mi][kh], bfl[ni][kh], acc[mi][ni], 0, 0, 0);
                    acc[mi][ni] = __builtin_amdgcn_mfma_f32_16x16x32_bf16(
                        afl[mi][kh], bfh[ni][kh], acc[mi][ni], 0, 0, 0);
                }
    }

    // ---- epilogue: C tile -> LDS (f32), norms, vn + vt ----
    __syncthreads();
    float* Ct = (float*)smem;                          // [64][68] pad
    #pragma unroll
    for (int mi = 0; mi < 2; ++mi)
        #pragma unroll
        for (int ni = 0; ni < 2; ++ni)
            #pragma unroll
            for (int i = 0; i < 4; ++i)
                Ct[(wm*32 + mi*16 + lg*4 + i) * 68 + wn*32 + ni*16 + rl] = acc[mi][ni][i];
    __syncthreads();

    const int bh = b * NH + h;
    {   // vn: thread t handles row t>>2, 16-col quarter t&3
        int row = tid >> 2, c = tid & 3;
        float x[16];
        #pragma unroll
        for (int j = 0; j < 4; ++j) {
            float4 v4 = *(const float4*)(Ct + row * 68 + c * 16 + j * 4);
            x[j*4+0] = v4.x; x[j*4+1] = v4.y; x[j*4+2] = v4.z; x[j*4+3] = v4.w;
        }
        float ss = 0.f;
        #pragma unroll
        for (int j = 0; j < 16; ++j) ss += x[j] * x[j];
        ss += __shfl_xor(ss, 1);
        ss += __shfl_xor(ss, 2);
        float rn = rsqrtf(ss);
        ushort8 o0, o1;
        #pragma unroll
        for (int j = 0; j < 8; ++j) { o0[j] = f2bf(x[j] * rn); o1[j] = f2bf(x[8 + j] * rn); }
        size_t base = ((size_t)bh * NTOK + n0 + row) * HD + c * 16;
        *(ushort8*)(vn + base)     = o0;
        *(ushort8*)(vn + base + 8) = o1;
    }
    {   // vt: thread t handles col d = t&63, 16-row segment t>>6
        int d = tid & 63, seg = tid >> 6;
        ushort8 o0, o1;
        #pragma unroll
        for (int j = 0; j < 8; ++j) {
            o0[j] = f2bf(Ct[(seg*16 + j)     * 68 + d]);
            o1[j] = f2bf(Ct[(seg*16 + 8 + j) * 68 + d]);
        }
        size_t base = ((size_t)bh * HD + d) * NTOK + n0 + seg * 16;
        *(ushort8*)(vt + base)     = o0;
        *(ushort8*)(vt + base + 8) = o1;
    }
}

// ---------------------------------------------------------------------------
// Fallback fp32 vproj (used only if ws_size can't hold the split arrays).
// ---------------------------------------------------------------------------
__global__ __launch_bounds__(256) void vproj_fp32_kernel(
    const float* __restrict__ q, const float* __restrict__ w,
    ushort* __restrict__ vn, ushort* __restrict__ vt)
{
    __shared__ __align__(16) char smem[2 * 32 * 65 * 4];
    float (*As)[65] = (float (*)[65])smem;
    float (*Bs)[65] = (float (*)[65])(smem + 32 * 65 * 4);
    const int h = blockIdx.x, mb = blockIdx.y;
    const int tid = threadIdx.x;
    const int tx = tid & 15, ty = tid >> 4;
    const int m0 = mb * 64, b = m0 >> 10;
    const int lk = tid & 31, lr = tid >> 5;
    float acc[4][4] = {};
    for (int kt = 0; kt < DM; kt += 32) {
        #pragma unroll
        for (int p = 0; p < 8; ++p) {
            int row = lr + p * 8;
            int n = (m0 + row) & (NTOK - 1);
            As[lk][row] = q[(size_t)(n * BATCH + b) * DM + kt + lk];
            Bs[lk][row] = w[(size_t)(h * HD + row) * DM + kt + lk];
        }
        __syncthreads();
        #pragma unroll 8
        for (int k = 0; k < 32; ++k) {
            float a0 = As[k][4*ty+0], a1 = As[k][4*ty+1];
            float a2 = As[k][4*ty+2], a3 = As[k][4*ty+3];
            float b0 = Bs[k][4*tx+0], b1 = Bs[k][4*tx+1];
            float b2 = Bs[k][4*tx+2], b3 = Bs[k][4*tx+3];
            acc[0][0]+=a0*b0; acc[0][1]+=a0*b1; acc[0][2]+=a0*b2; acc[0][3]+=a0*b3;
            acc[1][0]+=a1*b0; acc[1][1]+=a1*b1; acc[1][2]+=a1*b2; acc[1][3]+=a1*b3;
            acc[2][0]+=a2*b0; acc[2][1]+=a2*b1; acc[2][2]+=a2*b2; acc[2][3]+=a2*b3;
            acc[3][0]+=a3*b0; acc[3][1]+=a3*b1; acc[3][2]+=a3*b2; acc[3][3]+=a3*b3;
        }
        __syncthreads();
    }
    const int bh = b * NH + h;
    const int n0 = m0 & (NTOK - 1);
    #pragma unroll
    for (int i = 0; i < 4; ++i) {
        float ss = acc[i][0]*acc[i][0] + acc[i][1]*acc[i][1]
                 + acc[i][2]*acc[i][2] + acc[i][3]*acc[i][3];
        #pragma unroll
        for (int msk = 1; msk < 16; msk <<= 1) ss += __shfl_xor(ss, msk, 16);
        float rn = rsqrtf(ss);
        int n = n0 + 4*ty + i;
        ushort4 o;
        o.x = f2bf(acc[i][0]*rn); o.y = f2bf(acc[i][1]*rn);
        o.z = f2bf(acc[i][2]*rn); o.w = f2bf(acc[i][3]*rn);
        *(ushort4*)&vn[((size_t)bh * NTOK + n) * HD + 4*tx] = o;
    }
    ushort (*T)[72] = (ushort (*)[72])smem;
    #pragma unroll
    for (int i = 0; i < 4; ++i)
        #pragma unroll
        for (int j = 0; j < 4; ++j)
            T[4*tx + j][4*ty + i] = f2bf(acc[i][j]);
    __syncthreads();
    {
        int d = tid >> 2, c = tid & 3;
        uint4 lo = *(const uint4*)&T[d][c*16];
        uint4 hi = *(const uint4*)&T[d][c*16 + 8];
        size_t go = ((size_t)bh * HD + d) * NTOK + n0 + c*16;
        *(uint4*)&vt[go]     = lo;
        *(uint4*)&vt[go + 8] = hi;
    }
}

// ---------------------------------------------------------------------------
// Kernel 2: flash attention, bf16 MFMA (16x16x32), fp32 softmax. (unchanged)
// ---------------------------------------------------------------------------
__global__ __launch_bounds__(256) void attn_kernel(
    const ushort* __restrict__ vn, const ushort* __restrict__ vt,
    float* __restrict__ out)
{
    __shared__ __align__(16) ushort Klds[64 * 64];
    __shared__ __align__(16) ushort Vlds[64 * 64];
    __shared__ __align__(16) ushort Plds[4 * 16 * 64];
    const int bh  = blockIdx.y;
    const int q0  = blockIdx.x * 64;
    const int tid = threadIdx.x;
    const int wv  = tid >> 6;
    const int l   = tid & 63;
    const int rl  = l & 15, lg = l >> 4;

    const ushort* vb  = vn + (size_t)bh * NTOK * HD;
    const ushort* vtb = vt + (size_t)bh * HD * NTOK;
    ushort* Pw = Plds + wv * 16 * 64;

    short8 qf[2];
    {
        int qrow = q0 + wv*16 + rl;
        qf[0] = *(const short8*)(vb + (size_t)qrow * HD + lg*8);
        qf[1] = *(const short8*)(vb + (size_t)qrow * HD + 32 + lg*8);
    }

    f32x4 o_acc[4] = {};
    float m_run[4], l_run[4];
    #pragma unroll
    for (int i = 0; i < 4; ++i) { m_run[i] = -1e30f; l_run[i] = 0.f; }

    for (int kt = 0; kt < NTOK / 64; ++kt) {
        __syncthreads();
        #pragma unroll
        for (int rnd = 0; rnd < 2; ++rnd) {
            int chunk = rnd * 256 + tid;
            int r = chunk >> 3, c = chunk & 7;
            int slot = c ^ (r & 7);
            uint4 kk = *(const uint4*)(vb + (size_t)(kt*64 + r) * HD + c*8);
            *(uint4*)(Klds + r*64 + slot*8) = kk;
            uint4 vv = *(const uint4*)(vtb + (size_t)r * NTOK + kt*64 + c*8);
            *(uint4*)(Vlds + r*64 + slot*8) = vv;
        }
        __syncthreads();

        f32x4 s[4] = {};
        #pragma unroll
        for (int g = 0; g < 4; ++g) {
            int r = g*16 + rl;
            #pragma unroll
            for (int f = 0; f < 2; ++f) {
                int cc = f*4 + lg;
                short8 bk = *(const short8*)(Klds + r*64 + ((cc ^ (r & 7)) * 8));
                s[g] = __builtin_amdgcn_mfma_f32_16x16x32_bf16(qf[f], bk, s[g], 0, 0, 0);
            }
        }

        ushort pb[4][4];
        #pragma unroll
        for (int i = 0; i < 4; ++i) {
            float mx = -1e30f;
            #pragma unroll
            for (int g = 0; g < 4; ++g) { s[g][i] *= 0.125f; mx = fmaxf(mx, s[g][i]); }
            #pragma unroll
            for (int msk = 1; msk < 16; msk <<= 1)
                mx = fmaxf(mx, __shfl_xor(mx, msk, 16));
            float mnew = fmaxf(m_run[i], mx);
            float al   = __expf(m_run[i] - mnew);
            float ls = 0.f;
            #pragma unroll
            for (int g = 0; g < 4; ++g) {
                float p = __expf(s[g][i] - mnew);
                s[g][i] = p; ls += p;
            }
            #pragma unroll
            for (int msk = 1; msk < 16; msk <<= 1)
                ls += __shfl_xor(ls, msk, 16);
            l_run[i] = l_run[i] * al + ls;
            m_run[i] = mnew;
            #pragma unroll
            for (int dg = 0; dg < 4; ++dg) o_acc[dg][i] *= al;
            #pragma unroll
            for (int g = 0; g < 4; ++g) pb[g][i] = f2bf(s[g][i]);
        }

        #pragma unroll
        for (int g = 0; g < 4; ++g)
            #pragma unroll
            for (int i = 0; i < 4; ++i) {
                int row = lg*4 + i;
                int byr = (g*16 + rl) * 2;
                *(ushort*)((char*)Pw + row*128 + (byr ^ ((row & 7) << 4))) = pb[g][i];
            }

        #pragma unroll
        for (int kvg = 0; kvg < 2; ++kvg) {
            int pcc = kvg*4 + lg;
            short8 pa = *(const short8*)((const char*)Pw + rl*128 + ((pcc ^ (rl & 7)) * 16));
            #pragma unroll
            for (int dg = 0; dg < 4; ++dg) {
                int vr = dg*16 + rl;
                int vcc = kvg*4 + lg;
                short8 bv = *(const short8*)(Vlds + vr*64 + ((vcc ^ (vr & 7)) * 8));
                o_acc[dg] = __builtin_amdgcn_mfma_f32_16x16x32_bf16(pa, bv, o_acc[dg], 0, 0, 0);
            }
        }
    }

    const int b = bh / NH, h = bh % NH;
    #pragma unroll
    for (int i = 0; i < 4; ++i) {
        int n = q0 + wv*16 + lg*4 + i;
        float inv = 1.f / l_run[i];
        #pragma unroll
        for (int dg = 0; dg < 4; ++dg)
            out[((size_t)n * BATCH + b) * DM + h*HD + dg*16 + rl] = o_acc[dg][i] * inv;
    }
}

extern "C" void kernel_launch(void* const* d_in, const int* in_sizes, int n_in,
                              void* d_out, int out_size, void* d_ws, size_t ws_size,
                              hipStream_t stream) {
    const float* q = (const float*)d_in[0];   // [1024, 8, 768]
    const float* w = (const float*)d_in[1];   // [768, 768]
    float* out = (float*)d_out;               // [1024, 8, 768]

    const size_t QE = (size_t)NTOK * BATCH * DM;     // 6,291,456
    const size_t WE = (size_t)DM * DM;               //   589,824
    const size_t VE = (size_t)NH * BATCH * NTOK * HD;// 6,291,456

    ushort* vn = (ushort*)d_ws;
    ushort* vt = vn + VE;
    size_t need = (2 * VE + 2 * QE + 2 * WE) * sizeof(ushort);

    if (ws_size >= need) {
        ushort* qh = vt + VE;
        ushort* ql = qh + QE;
        ushort* wh = ql + QE;
        ushort* wl = wh + WE;
        split_q_kernel<<<(QE / 8 + 255) / 256, 256, 0, stream>>>(q, qh, ql);
        split_w_kernel<<<(WE / 8 + 255) / 256, 256, 0, stream>>>(w, wh, wl);
        vproj_mfma_kernel<<<dim3(NH, (BATCH * NTOK) / 64), 256, 0, stream>>>(
            qh, ql, wh, wl, vn, vt);
    } else {
        vproj_fp32_kernel<<<dim3(NH, (BATCH * NTOK) / 64), 256, 0, stream>>>(q, w, vn, vt);
    }
    attn_kernel<<<dim3(NTOK / 64, BATCH * NH), 256, 0, stream>>>(vn, vt, out);
}

// Round 5
// 110.459 us; speedup vs baseline: 6.5742x; 1.3280x over previous
//
#include <hip/hip_runtime.h>
#include <hip/hip_bf16.h>

#define NH    12
#define HD    64
#define NTOK  1024
#define BATCH 8
#define DM    768

typedef short  short8  __attribute__((ext_vector_type(8)));
typedef float  f32x4   __attribute__((ext_vector_type(4)));
typedef float  f32x16  __attribute__((ext_vector_type(16)));
typedef unsigned short ushort8 __attribute__((ext_vector_type(8)));

__device__ __forceinline__ ushort f2bf(float f) {
    union { float f; unsigned u; } x; x.f = f;
    unsigned r = x.u + 0x7FFF + ((x.u >> 16) & 1);   // RNE
    return (ushort)(r >> 16);
}
__device__ __forceinline__ float bf2f(ushort h) {
    union { unsigned u; float f; } x; x.u = ((unsigned)h) << 16;
    return x.f;
}
__device__ __forceinline__ void gl_lds16(const ushort* g, ushort* l) {
    __builtin_amdgcn_global_load_lds(
        (const __attribute__((address_space(1))) unsigned int*)g,
        (__attribute__((address_space(3))) unsigned int*)l, 16, 0, 0);
}
__device__ __forceinline__ f32x16 mfma32(short8 a, short8 b, f32x16 c) {
    return __builtin_amdgcn_mfma_f32_32x32x16_bf16(a, b, c, 0, 0, 0);
}

// ---------------------------------------------------------------------------
// Split kernels: x -> (hi, lo) bf16 with hi = bf16(x), lo = bf16(x - hi).
// q is also transposed [n][b][d] -> [b][n][d] so GEMM tile rows are contiguous.
// ---------------------------------------------------------------------------
__global__ __launch_bounds__(256) void split_q_kernel(
    const float* __restrict__ src, ushort* __restrict__ hi, ushort* __restrict__ lo)
{
    int t = blockIdx.x * 256 + threadIdx.x;       // 786432 threads, 8 elems each
    int dblk = t % 96; int nb = t / 96; int b = nb & 7; int n = nb >> 3;
    const float* s = src + (size_t)t * 8;
    size_t o = ((size_t)(b * 1024 + n) * 96 + dblk) * 8;
    float4 x0 = *(const float4*)s, x1 = *(const float4*)(s + 4);
    float xs[8] = {x0.x, x0.y, x0.z, x0.w, x1.x, x1.y, x1.z, x1.w};
    ushort8 h8, l8;
    #pragma unroll
    for (int j = 0; j < 8; ++j) {
        ushort h = f2bf(xs[j]);
        h8[j] = h;
        l8[j] = f2bf(xs[j] - bf2f(h));
    }
    *(ushort8*)(hi + o) = h8;
    *(ushort8*)(lo + o) = l8;
}

__global__ __launch_bounds__(256) void split_w_kernel(
    const float* __restrict__ src, ushort* __restrict__ hi, ushort* __restrict__ lo)
{
    int t = blockIdx.x * 256 + threadIdx.x;       // 73728 threads
    const float* s = src + (size_t)t * 8;
    float4 x0 = *(const float4*)s, x1 = *(const float4*)(s + 4);
    float xs[8] = {x0.x, x0.y, x0.z, x0.w, x1.x, x1.y, x1.z, x1.w};
    ushort8 h8, l8;
    #pragma unroll
    for (int j = 0; j < 8; ++j) {
        ushort h = f2bf(xs[j]);
        h8[j] = h;
        l8[j] = f2bf(xs[j] - bf2f(h));
    }
    size_t o = (size_t)t * 8;
    *(ushort8*)(hi + o) = h8;
    *(ushort8*)(lo + o) = l8;
}

// ---------------------------------------------------------------------------
// vproj via split-bf16 MFMA: C = Ah.Bh + Ah.Bl + Al.Bh  (fp32 accum).
// ---------------------------------------------------------------------------
__global__ __launch_bounds__(256) void vproj_mfma_kernel(
    const ushort* __restrict__ qh, const ushort* __restrict__ ql,
    const ushort* __restrict__ wh, const ushort* __restrict__ wl,
    ushort* __restrict__ vn, ushort* __restrict__ vt)
{
    __shared__ __align__(16) char smem[32768];
    ushort* Ah = (ushort*)smem;
    ushort* Al = (ushort*)(smem + 8192);
    ushort* Bh = (ushort*)(smem + 16384);
    ushort* Bl = (ushort*)(smem + 24576);
    const int h   = blockIdx.x, mb = blockIdx.y;
    const int tid = threadIdx.x, wv = tid >> 6, l = tid & 63;
    const int rl  = l & 15, lg = l >> 4;
    const int wm  = wv >> 1, wn = wv & 1;
    const int b   = mb >> 4, n0 = (mb & 15) * 64;

    const ushort* gsrc; ushort* ltile; size_t srow0;
    if (wv == 0)      { gsrc = qh; ltile = Ah; srow0 = (size_t)(b * 1024 + n0); }
    else if (wv == 1) { gsrc = ql; ltile = Al; srow0 = (size_t)(b * 1024 + n0); }
    else if (wv == 2) { gsrc = wh; ltile = Bh; srow0 = (size_t)(h * 64); }
    else              { gsrc = wl; ltile = Bl; srow0 = (size_t)(h * 64); }

    f32x4 acc[2][2] = {};

    for (int kt = 0; kt < 12; ++kt) {
        __syncthreads();
        #pragma unroll
        for (int p = 0; p < 8; ++p) {
            int r = p * 8 + (l >> 3);
            int c = (l & 7) ^ (r & 7);                // inverse-swizzled source
            gl_lds16(gsrc + (srow0 + r) * 768 + kt * 64 + c * 8,
                     ltile + p * 512);                // linear LDS dest
        }
        __syncthreads();

        short8 afh[2][2], afl[2][2], bfh[2][2], bfl[2][2];
        #pragma unroll
        for (int mi = 0; mi < 2; ++mi)
            #pragma unroll
            for (int kh = 0; kh < 2; ++kh) {
                int cc = kh * 4 + lg;
                int ra = wm * 32 + mi * 16 + rl;
                int sa = (cc ^ (ra & 7)) * 8;
                afh[mi][kh] = *(const short8*)(Ah + ra * 64 + sa);
                afl[mi][kh] = *(const short8*)(Al + ra * 64 + sa);
                int rb = wn * 32 + mi * 16 + rl;
                int sb = (cc ^ (rb & 7)) * 8;
                bfh[mi][kh] = *(const short8*)(Bh + rb * 64 + sb);
                bfl[mi][kh] = *(const short8*)(Bl + rb * 64 + sb);
            }
        #pragma unroll
        for (int mi = 0; mi < 2; ++mi)
            #pragma unroll
            for (int ni = 0; ni < 2; ++ni)
                #pragma unroll
                for (int kh = 0; kh < 2; ++kh) {
                    acc[mi][ni] = __builtin_amdgcn_mfma_f32_16x16x32_bf16(
                        afh[mi][kh], bfh[ni][kh], acc[mi][ni], 0, 0, 0);
                    acc[mi][ni] = __builtin_amdgcn_mfma_f32_16x16x32_bf16(
                        afh[mi][kh], bfl[ni][kh], acc[mi][ni], 0, 0, 0);
                    acc[mi][ni] = __builtin_amdgcn_mfma_f32_16x16x32_bf16(
                        afl[mi][kh], bfh[ni][kh], acc[mi][ni], 0, 0, 0);
                }
    }

    __syncthreads();
    float* Ct = (float*)smem;                          // [64][68] pad
    #pragma unroll
    for (int mi = 0; mi < 2; ++mi)
        #pragma unroll
        for (int ni = 0; ni < 2; ++ni)
            #pragma unroll
            for (int i = 0; i < 4; ++i)
                Ct[(wm*32 + mi*16 + lg*4 + i) * 68 + wn*32 + ni*16 + rl] = acc[mi][ni][i];
    __syncthreads();

    const int bh = b * NH + h;
    {   // vn: thread t handles row t>>2, 16-col quarter t&3
        int row = tid >> 2, c = tid & 3;
        float x[16];
        #pragma unroll
        for (int j = 0; j < 4; ++j) {
            float4 v4 = *(const float4*)(Ct + row * 68 + c * 16 + j * 4);
            x[j*4+0] = v4.x; x[j*4+1] = v4.y; x[j*4+2] = v4.z; x[j*4+3] = v4.w;
        }
        float ss = 0.f;
        #pragma unroll
        for (int j = 0; j < 16; ++j) ss += x[j] * x[j];
        ss += __shfl_xor(ss, 1);
        ss += __shfl_xor(ss, 2);
        float rn = rsqrtf(ss);
        ushort8 o0, o1;
        #pragma unroll
        for (int j = 0; j < 8; ++j) { o0[j] = f2bf(x[j] * rn); o1[j] = f2bf(x[8 + j] * rn); }
        size_t base = ((size_t)bh * NTOK + n0 + row) * HD + c * 16;
        *(ushort8*)(vn + base)     = o0;
        *(ushort8*)(vn + base + 8) = o1;
    }
    {   // vt: thread t handles col d = t&63, 16-row segment t>>6
        int d = tid & 63, seg = tid >> 6;
        ushort8 o0, o1;
        #pragma unroll
        for (int j = 0; j < 8; ++j) {
            o0[j] = f2bf(Ct[(seg*16 + j)     * 68 + d]);
            o1[j] = f2bf(Ct[(seg*16 + 8 + j) * 68 + d]);
        }
        size_t base = ((size_t)bh * HD + d) * NTOK + n0 + seg * 16;
        *(ushort8*)(vt + base)     = o0;
        *(ushort8*)(vt + base + 8) = o1;
    }
}

// ---------------------------------------------------------------------------
// Fallback fp32 vproj (used only if ws_size can't hold the split arrays).
// ---------------------------------------------------------------------------
__global__ __launch_bounds__(256) void vproj_fp32_kernel(
    const float* __restrict__ q, const float* __restrict__ w,
    ushort* __restrict__ vn, ushort* __restrict__ vt)
{
    __shared__ __align__(16) char smem[2 * 32 * 65 * 4];
    float (*As)[65] = (float (*)[65])smem;
    float (*Bs)[65] = (float (*)[65])(smem + 32 * 65 * 4);
    const int h = blockIdx.x, mb = blockIdx.y;
    const int tid = threadIdx.x;
    const int tx = tid & 15, ty = tid >> 4;
    const int m0 = mb * 64, b = m0 >> 10;
    const int lk = tid & 31, lr = tid >> 5;
    float acc[4][4] = {};
    for (int kt = 0; kt < DM; kt += 32) {
        #pragma unroll
        for (int p = 0; p < 8; ++p) {
            int row = lr + p * 8;
            int n = (m0 + row) & (NTOK - 1);
            As[lk][row] = q[(size_t)(n * BATCH + b) * DM + kt + lk];
            Bs[lk][row] = w[(size_t)(h * HD + row) * DM + kt + lk];
        }
        __syncthreads();
        #pragma unroll 8
        for (int k = 0; k < 32; ++k) {
            float a0 = As[k][4*ty+0], a1 = As[k][4*ty+1];
            float a2 = As[k][4*ty+2], a3 = As[k][4*ty+3];
            float b0 = Bs[k][4*tx+0], b1 = Bs[k][4*tx+1];
            float b2 = Bs[k][4*tx+2], b3 = Bs[k][4*tx+3];
            acc[0][0]+=a0*b0; acc[0][1]+=a0*b1; acc[0][2]+=a0*b2; acc[0][3]+=a0*b3;
            acc[1][0]+=a1*b0; acc[1][1]+=a1*b1; acc[1][2]+=a1*b2; acc[1][3]+=a1*b3;
            acc[2][0]+=a2*b0; acc[2][1]+=a2*b1; acc[2][2]+=a2*b2; acc[2][3]+=a2*b3;
            acc[3][0]+=a3*b0; acc[3][1]+=a3*b1; acc[3][2]+=a3*b2; acc[3][3]+=a3*b3;
        }
        __syncthreads();
    }
    const int bh = b * NH + h;
    const int n0 = m0 & (NTOK - 1);
    #pragma unroll
    for (int i = 0; i < 4; ++i) {
        float ss = acc[i][0]*acc[i][0] + acc[i][1]*acc[i][1]
                 + acc[i][2]*acc[i][2] + acc[i][3]*acc[i][3];
        #pragma unroll
        for (int msk = 1; msk < 16; msk <<= 1) ss += __shfl_xor(ss, msk, 16);
        float rn = rsqrtf(ss);
        int n = n0 + 4*ty + i;
        ushort4 o;
        o.x = f2bf(acc[i][0]*rn); o.y = f2bf(acc[i][1]*rn);
        o.z = f2bf(acc[i][2]*rn); o.w = f2bf(acc[i][3]*rn);
        *(ushort4*)&vn[((size_t)bh * NTOK + n) * HD + 4*tx] = o;
    }
    ushort (*T)[72] = (ushort (*)[72])smem;
    #pragma unroll
    for (int i = 0; i < 4; ++i)
        #pragma unroll
        for (int j = 0; j < 4; ++j)
            T[4*tx + j][4*ty + i] = f2bf(acc[i][j]);
    __syncthreads();
    {
        int d = tid >> 2, c = tid & 3;
        uint4 lo = *(const uint4*)&T[d][c*16];
        uint4 hi = *(const uint4*)&T[d][c*16 + 8];
        size_t go = ((size_t)bh * HD + d) * NTOK + n0 + c*16;
        *(uint4*)&vt[go]     = lo;
        *(uint4*)&vt[go + 8] = hi;
    }
}

// ---------------------------------------------------------------------------
// Kernel 2: flash attention, m214-style 32x32 structure.
// 4 waves x 32 q-rows (Q-tile 128), KV-tile 64. Swapped QK^T (S^T via
// mfma(A=K,B=Q)) -> one q-row per lane -> in-lane softmax + one shfl_xor(32).
// P rebuilt in-register via cvt_pk_bf16 + permlane32_swap -> PV computes O^T
// with V^T (vt layout) as A-operand. No P-LDS roundtrip. T14 async staging.
// LDS = K(8KB) + V(8KB), XOR-swizzled 16B chunks.
// ---------------------------------------------------------------------------
__global__ __launch_bounds__(256) void attn_kernel(
    const ushort* __restrict__ vn, const ushort* __restrict__ vt,
    float* __restrict__ out)
{
    __shared__ __align__(16) ushort Klds[64 * 64];   // [kv][d], swizzled
    __shared__ __align__(16) ushort Vlds[64 * 64];   // [d][kv], swizzled
    const int bh  = blockIdx.y;
    const int q0  = blockIdx.x * 128;
    const int tid = threadIdx.x;
    const int wv  = tid >> 6;
    const int l   = tid & 63;
    const int ql  = l & 31;          // q column (one q-row per lane)
    const int h   = l >> 5;          // half

    const ushort* vb  = vn + (size_t)bh * NTOK * HD;
    const ushort* vtb = vt + (size_t)bh * HD * NTOK;

    // Q B-frags: B[k=d][n=q], lane holds d = 16ks + 8h + j of row q0+wv*32+ql
    short8 qB[4];
    {
        int qrow = q0 + wv * 32 + ql;
        #pragma unroll
        for (int ks = 0; ks < 4; ++ks)
            qB[ks] = *(const short8*)(vb + (size_t)qrow * HD + ks * 16 + h * 8);
    }

    // staging geometry: chunk ch in {tid, tid+256}; r = ch>>3, c = ch&7
    const int sr0 = tid >> 3, sr1 = sr0 + 32;
    const int sc  = tid & 7;
    const int slt = (sc ^ (sr0 & 7)) * 8;            // sr1&7 == sr0&7
    uint4 kreg0, kreg1, vreg0, vreg1;

    f32x16 oT[2] = {};
    float m2 = -1e30f, lr = 0.f;
    const float CS = 0.18033688f;                     // 0.125 * log2(e)

    // prologue: stage tile 0
    kreg0 = *(const uint4*)(vb + (size_t)sr0 * HD + sc * 8);
    kreg1 = *(const uint4*)(vb + (size_t)sr1 * HD + sc * 8);
    vreg0 = *(const uint4*)(vtb + (size_t)sr0 * NTOK + sc * 8);
    vreg1 = *(const uint4*)(vtb + (size_t)sr1 * NTOK + sc * 8);
    *(uint4*)(Klds + sr0 * 64 + slt) = kreg0;
    *(uint4*)(Klds + sr1 * 64 + slt) = kreg1;
    *(uint4*)(Vlds + sr0 * 64 + slt) = vreg0;
    *(uint4*)(Vlds + sr1 * 64 + slt) = vreg1;
    __syncthreads();

    for (int kt = 0; kt < NTOK / 64; ++kt) {
        // T14: issue next tile's global loads early (latency hides under MFMA)
        if (kt < NTOK / 64 - 1) {
            int kb = (kt + 1) * 64;
            kreg0 = *(const uint4*)(vb + (size_t)(kb + sr0) * HD + sc * 8);
            kreg1 = *(const uint4*)(vb + (size_t)(kb + sr1) * HD + sc * 8);
            vreg0 = *(const uint4*)(vtb + (size_t)sr0 * NTOK + kb + sc * 8);
            vreg1 = *(const uint4*)(vtb + (size_t)sr1 * NTOK + kb + sc * 8);
        }

        // S^T = K . Q : st[g] covers kv = 32g + (r&3)+8*(r>>2)+4h, q = ql
        f32x16 st[2] = {};
        #pragma unroll
        for (int ks = 0; ks < 4; ++ks) {
            int so = ((2 * ks + h) ^ (ql & 7)) * 8;
            short8 k0 = *(const short8*)(Klds + ql * 64 + so);
            short8 k1 = *(const short8*)(Klds + (32 + ql) * 64 + so);
            st[0] = mfma32(k0, qB[ks], st[0]);
            st[1] = mfma32(k1, qB[ks], st[1]);
        }

        // online softmax, one q-row per lane (in-lane tree + 1 cross-half shfl)
        float tm[16];
        #pragma unroll
        for (int i = 0; i < 16; ++i) tm[i] = fmaxf(st[0][i], st[1][i]);
        #pragma unroll
        for (int s = 8; s >= 1; s >>= 1)
            #pragma unroll
            for (int i = 0; i < s; ++i) tm[i] = fmaxf(tm[i], tm[i + s]);
        float mx = fmaxf(tm[0], __shfl_xor(tm[0], 32));
        float m2n = fmaxf(m2, mx * CS);
        float al = __builtin_amdgcn_exp2f(m2 - m2n);
        m2 = m2n;
        #pragma unroll
        for (int g = 0; g < 2; ++g)
            #pragma unroll
            for (int i = 0; i < 16; ++i)
                st[g][i] = __builtin_amdgcn_exp2f(fmaf(st[g][i], CS, -m2n));
        float ts[16];
        #pragma unroll
        for (int i = 0; i < 16; ++i) ts[i] = st[0][i] + st[1][i];
        #pragma unroll
        for (int s = 8; s >= 1; s >>= 1)
            #pragma unroll
            for (int i = 0; i < s; ++i) ts[i] += ts[i + s];
        lr = lr * al + (ts[0] + __shfl_xor(ts[0], 32));
        #pragma unroll
        for (int i = 0; i < 16; ++i) { oT[0][i] *= al; oT[1][i] *= al; }

        // pack P to bf16 pairs: pb2[g][t][u] = (p[4t+2u], p[4t+2u+1]) of st[g]
        unsigned pb2[2][4][2];
        #pragma unroll
        for (int g = 0; g < 2; ++g)
            #pragma unroll
            for (int t = 0; t < 4; ++t)
                #pragma unroll
                for (int u = 0; u < 2; ++u)
                    asm("v_cvt_pk_bf16_f32 %0, %1, %2"
                        : "=v"(pb2[g][t][u])
                        : "v"(st[g][4 * t + 2 * u]), "v"(st[g][4 * t + 2 * u + 1]));

        // O^T += V^T . P^T : per 16-kv step s, B-frag built by permlane32_swap
        #pragma unroll
        for (int s = 0; s < 4; ++s) {
            const int g = s >> 1, sp = s & 1;
            unsigned x0 = pb2[g][2 * sp][0], y0 = pb2[g][2 * sp + 1][0];
            unsigned x1 = pb2[g][2 * sp][1], y1 = pb2[g][2 * sp + 1][1];
            asm volatile("v_permlane32_swap_b32 %0, %1" : "+v"(x0), "+v"(y0));
            asm volatile("v_permlane32_swap_b32 %0, %1" : "+v"(x1), "+v"(y1));
            union { unsigned u[4]; short8 s8; } pb;
            pb.u[0] = x0; pb.u[1] = x1; pb.u[2] = y0; pb.u[3] = y1;
            int so = ((2 * s + h) ^ (ql & 7)) * 8;
            short8 v0 = *(const short8*)(Vlds + ql * 64 + so);
            short8 v1 = *(const short8*)(Vlds + (32 + ql) * 64 + so);
            oT[0] = mfma32(v0, pb.s8, oT[0]);
            oT[1] = mfma32(v1, pb.s8, oT[1]);
        }

        __syncthreads();                 // all waves done reading tile kt
        if (kt < NTOK / 64 - 1) {
            *(uint4*)(Klds + sr0 * 64 + slt) = kreg0;
            *(uint4*)(Klds + sr1 * 64 + slt) = kreg1;
            *(uint4*)(Vlds + sr0 * 64 + slt) = vreg0;
            *(uint4*)(Vlds + sr1 * 64 + slt) = vreg1;
            __syncthreads();
        }
    }

    // epilogue: out[n][b][hh*64+d] = O^T[d][q] / lr ; d = 32dm + 8t + 4h + e
    const int b = bh / NH, hh = bh % NH;
    const float inv = 1.f / lr;
    int n = q0 + wv * 32 + ql;
    float* orow = out + ((size_t)n * BATCH + b) * DM + hh * HD;
    #pragma unroll
    for (int dm = 0; dm < 2; ++dm)
        #pragma unroll
        for (int t = 0; t < 4; ++t) {
            float4 val = make_float4(oT[dm][4 * t] * inv, oT[dm][4 * t + 1] * inv,
                                     oT[dm][4 * t + 2] * inv, oT[dm][4 * t + 3] * inv);
            *(float4*)(orow + dm * 32 + t * 8 + h * 4) = val;
        }
}

extern "C" void kernel_launch(void* const* d_in, const int* in_sizes, int n_in,
                              void* d_out, int out_size, void* d_ws, size_t ws_size,
                              hipStream_t stream) {
    const float* q = (const float*)d_in[0];   // [1024, 8, 768]
    const float* w = (const float*)d_in[1];   // [768, 768]
    float* out = (float*)d_out;               // [1024, 8, 768]

    const size_t QE = (size_t)NTOK * BATCH * DM;     // 6,291,456
    const size_t WE = (size_t)DM * DM;               //   589,824
    const size_t VE = (size_t)NH * BATCH * NTOK * HD;// 6,291,456

    ushort* vn = (ushort*)d_ws;
    ushort* vt = vn + VE;
    size_t need = (2 * VE + 2 * QE + 2 * WE) * sizeof(ushort);

    if (ws_size >= need) {
        ushort* qh = vt + VE;
        ushort* ql = qh + QE;
        ushort* wh = ql + QE;
        ushort* wl = wh + WE;
        split_q_kernel<<<(QE / 8 + 255) / 256, 256, 0, stream>>>(q, qh, ql);
        split_w_kernel<<<(WE / 8 + 255) / 256, 256, 0, stream>>>(w, wh, wl);
        vproj_mfma_kernel<<<dim3(NH, (BATCH * NTOK) / 64), 256, 0, stream>>>(
            qh, ql, wh, wl, vn, vt);
    } else {
        vproj_fp32_kernel<<<dim3(NH, (BATCH * NTOK) / 64), 256, 0, stream>>>(q, w, vn, vt);
    }
    attn_kernel<<<dim3(NTOK / 128, BATCH * NH), 256, 0, stream>>>(vn, vt, out);
}

// Round 6
// 103.713 us; speedup vs baseline: 7.0018x; 1.0650x over previous
//
#include <hip/hip_runtime.h>
#include <hip/hip_bf16.h>

#define NH    12
#define HD    64
#define NTOK  1024
#define BATCH 8
#define DM    768

typedef short  short8  __attribute__((ext_vector_type(8)));
typedef float  f32x4   __attribute__((ext_vector_type(4)));
typedef float  f32x16  __attribute__((ext_vector_type(16)));
typedef unsigned short ushort8 __attribute__((ext_vector_type(8)));

__device__ __forceinline__ ushort f2bf(float f) {
    union { float f; unsigned u; } x; x.f = f;
    unsigned r = x.u + 0x7FFF + ((x.u >> 16) & 1);   // RNE
    return (ushort)(r >> 16);
}
__device__ __forceinline__ float bf2f(ushort h) {
    union { unsigned u; float f; } x; x.u = ((unsigned)h) << 16;
    return x.f;
}
__device__ __forceinline__ void gl_lds16(const ushort* g, ushort* l) {
    __builtin_amdgcn_global_load_lds(
        (const __attribute__((address_space(1))) unsigned int*)g,
        (__attribute__((address_space(3))) unsigned int*)l, 16, 0, 0);
}
__device__ __forceinline__ f32x16 mfma32(short8 a, short8 b, f32x16 c) {
    return __builtin_amdgcn_mfma_f32_32x32x16_bf16(a, b, c, 0, 0, 0);
}

// ---------------------------------------------------------------------------
// Split kernels: x -> (hi, lo) bf16 with hi = bf16(x), lo = bf16(x - hi).
// q is also transposed [n][b][d] -> [b][n][d] so GEMM tile rows are contiguous.
// ---------------------------------------------------------------------------
__global__ __launch_bounds__(256) void split_q_kernel(
    const float* __restrict__ src, ushort* __restrict__ hi, ushort* __restrict__ lo)
{
    int t = blockIdx.x * 256 + threadIdx.x;       // 786432 threads, 8 elems each
    int dblk = t % 96; int nb = t / 96; int b = nb & 7; int n = nb >> 3;
    const float* s = src + (size_t)t * 8;
    size_t o = ((size_t)(b * 1024 + n) * 96 + dblk) * 8;
    float4 x0 = *(const float4*)s, x1 = *(const float4*)(s + 4);
    float xs[8] = {x0.x, x0.y, x0.z, x0.w, x1.x, x1.y, x1.z, x1.w};
    ushort8 h8, l8;
    #pragma unroll
    for (int j = 0; j < 8; ++j) {
        ushort h = f2bf(xs[j]);
        h8[j] = h;
        l8[j] = f2bf(xs[j] - bf2f(h));
    }
    *(ushort8*)(hi + o) = h8;
    *(ushort8*)(lo + o) = l8;
}

__global__ __launch_bounds__(256) void split_w_kernel(
    const float* __restrict__ src, ushort* __restrict__ hi, ushort* __restrict__ lo)
{
    int t = blockIdx.x * 256 + threadIdx.x;       // 73728 threads
    const float* s = src + (size_t)t * 8;
    float4 x0 = *(const float4*)s, x1 = *(const float4*)(s + 4);
    float xs[8] = {x0.x, x0.y, x0.z, x0.w, x1.x, x1.y, x1.z, x1.w};
    ushort8 h8, l8;
    #pragma unroll
    for (int j = 0; j < 8; ++j) {
        ushort h = f2bf(xs[j]);
        h8[j] = h;
        l8[j] = f2bf(xs[j] - bf2f(h));
    }
    size_t o = (size_t)t * 8;
    *(ushort8*)(hi + o) = h8;
    *(ushort8*)(lo + o) = l8;
}

// ---------------------------------------------------------------------------
// vproj via split-bf16 MFMA: C = Ah.Bh + Ah.Bl + Al.Bh  (fp32 accum).
// ---------------------------------------------------------------------------
__global__ __launch_bounds__(256) void vproj_mfma_kernel(
    const ushort* __restrict__ qh, const ushort* __restrict__ ql,
    const ushort* __restrict__ wh, const ushort* __restrict__ wl,
    ushort* __restrict__ vn, ushort* __restrict__ vt)
{
    __shared__ __align__(16) char smem[32768];
    ushort* Ah = (ushort*)smem;
    ushort* Al = (ushort*)(smem + 8192);
    ushort* Bh = (ushort*)(smem + 16384);
    ushort* Bl = (ushort*)(smem + 24576);
    const int h   = blockIdx.x, mb = blockIdx.y;
    const int tid = threadIdx.x, wv = tid >> 6, l = tid & 63;
    const int rl  = l & 15, lg = l >> 4;
    const int wm  = wv >> 1, wn = wv & 1;
    const int b   = mb >> 4, n0 = (mb & 15) * 64;

    const ushort* gsrc; ushort* ltile; size_t srow0;
    if (wv == 0)      { gsrc = qh; ltile = Ah; srow0 = (size_t)(b * 1024 + n0); }
    else if (wv == 1) { gsrc = ql; ltile = Al; srow0 = (size_t)(b * 1024 + n0); }
    else if (wv == 2) { gsrc = wh; ltile = Bh; srow0 = (size_t)(h * 64); }
    else              { gsrc = wl; ltile = Bl; srow0 = (size_t)(h * 64); }

    f32x4 acc[2][2] = {};

    for (int kt = 0; kt < 12; ++kt) {
        __syncthreads();
        #pragma unroll
        for (int p = 0; p < 8; ++p) {
            int r = p * 8 + (l >> 3);
            int c = (l & 7) ^ (r & 7);                // inverse-swizzled source
            gl_lds16(gsrc + (srow0 + r) * 768 + kt * 64 + c * 8,
                     ltile + p * 512);                // linear LDS dest
        }
        __syncthreads();

        short8 afh[2][2], afl[2][2], bfh[2][2], bfl[2][2];
        #pragma unroll
        for (int mi = 0; mi < 2; ++mi)
            #pragma unroll
            for (int kh = 0; kh < 2; ++kh) {
                int cc = kh * 4 + lg;
                int ra = wm * 32 + mi * 16 + rl;
                int sa = (cc ^ (ra & 7)) * 8;
                afh[mi][kh] = *(const short8*)(Ah + ra * 64 + sa);
                afl[mi][kh] = *(const short8*)(Al + ra * 64 + sa);
                int rb = wn * 32 + mi * 16 + rl;
                int sb = (cc ^ (rb & 7)) * 8;
                bfh[mi][kh] = *(const short8*)(Bh + rb * 64 + sb);
                bfl[mi][kh] = *(const short8*)(Bl + rb * 64 + sb);
            }
        #pragma unroll
        for (int mi = 0; mi < 2; ++mi)
            #pragma unroll
            for (int ni = 0; ni < 2; ++ni)
                #pragma unroll
                for (int kh = 0; kh < 2; ++kh) {
                    acc[mi][ni] = __builtin_amdgcn_mfma_f32_16x16x32_bf16(
                        afh[mi][kh], bfh[ni][kh], acc[mi][ni], 0, 0, 0);
                    acc[mi][ni] = __builtin_amdgcn_mfma_f32_16x16x32_bf16(
                        afh[mi][kh], bfl[ni][kh], acc[mi][ni], 0, 0, 0);
                    acc[mi][ni] = __builtin_amdgcn_mfma_f32_16x16x32_bf16(
                        afl[mi][kh], bfh[ni][kh], acc[mi][ni], 0, 0, 0);
                }
    }

    __syncthreads();
    float* Ct = (float*)smem;                          // [64][68] pad
    #pragma unroll
    for (int mi = 0; mi < 2; ++mi)
        #pragma unroll
        for (int ni = 0; ni < 2; ++ni)
            #pragma unroll
            for (int i = 0; i < 4; ++i)
                Ct[(wm*32 + mi*16 + lg*4 + i) * 68 + wn*32 + ni*16 + rl] = acc[mi][ni][i];
    __syncthreads();

    const int bh = b * NH + h;
    {   // vn: thread t handles row t>>2, 16-col quarter t&3
        int row = tid >> 2, c = tid & 3;
        float x[16];
        #pragma unroll
        for (int j = 0; j < 4; ++j) {
            float4 v4 = *(const float4*)(Ct + row * 68 + c * 16 + j * 4);
            x[j*4+0] = v4.x; x[j*4+1] = v4.y; x[j*4+2] = v4.z; x[j*4+3] = v4.w;
        }
        float ss = 0.f;
        #pragma unroll
        for (int j = 0; j < 16; ++j) ss += x[j] * x[j];
        ss += __shfl_xor(ss, 1);
        ss += __shfl_xor(ss, 2);
        float rn = rsqrtf(ss);
        ushort8 o0, o1;
        #pragma unroll
        for (int j = 0; j < 8; ++j) { o0[j] = f2bf(x[j] * rn); o1[j] = f2bf(x[8 + j] * rn); }
        size_t base = ((size_t)bh * NTOK + n0 + row) * HD + c * 16;
        *(ushort8*)(vn + base)     = o0;
        *(ushort8*)(vn + base + 8) = o1;
    }
    {   // vt: thread t handles col d = t&63, 16-row segment t>>6
        int d = tid & 63, seg = tid >> 6;
        ushort8 o0, o1;
        #pragma unroll
        for (int j = 0; j < 8; ++j) {
            o0[j] = f2bf(Ct[(seg*16 + j)     * 68 + d]);
            o1[j] = f2bf(Ct[(seg*16 + 8 + j) * 68 + d]);
        }
        size_t base = ((size_t)bh * HD + d) * NTOK + n0 + seg * 16;
        *(ushort8*)(vt + base)     = o0;
        *(ushort8*)(vt + base + 8) = o1;
    }
}

// ---------------------------------------------------------------------------
// Fallback fp32 vproj (used only if ws_size can't hold the split arrays).
// ---------------------------------------------------------------------------
__global__ __launch_bounds__(256) void vproj_fp32_kernel(
    const float* __restrict__ q, const float* __restrict__ w,
    ushort* __restrict__ vn, ushort* __restrict__ vt)
{
    __shared__ __align__(16) char smem[2 * 32 * 65 * 4];
    float (*As)[65] = (float (*)[65])smem;
    float (*Bs)[65] = (float (*)[65])(smem + 32 * 65 * 4);
    const int h = blockIdx.x, mb = blockIdx.y;
    const int tid = threadIdx.x;
    const int tx = tid & 15, ty = tid >> 4;
    const int m0 = mb * 64, b = m0 >> 10;
    const int lk = tid & 31, lr = tid >> 5;
    float acc[4][4] = {};
    for (int kt = 0; kt < DM; kt += 32) {
        #pragma unroll
        for (int p = 0; p < 8; ++p) {
            int row = lr + p * 8;
            int n = (m0 + row) & (NTOK - 1);
            As[lk][row] = q[(size_t)(n * BATCH + b) * DM + kt + lk];
            Bs[lk][row] = w[(size_t)(h * HD + row) * DM + kt + lk];
        }
        __syncthreads();
        #pragma unroll 8
        for (int k = 0; k < 32; ++k) {
            float a0 = As[k][4*ty+0], a1 = As[k][4*ty+1];
            float a2 = As[k][4*ty+2], a3 = As[k][4*ty+3];
            float b0 = Bs[k][4*tx+0], b1 = Bs[k][4*tx+1];
            float b2 = Bs[k][4*tx+2], b3 = Bs[k][4*tx+3];
            acc[0][0]+=a0*b0; acc[0][1]+=a0*b1; acc[0][2]+=a0*b2; acc[0][3]+=a0*b3;
            acc[1][0]+=a1*b0; acc[1][1]+=a1*b1; acc[1][2]+=a1*b2; acc[1][3]+=a1*b3;
            acc[2][0]+=a2*b0; acc[2][1]+=a2*b1; acc[2][2]+=a2*b2; acc[2][3]+=a2*b3;
            acc[3][0]+=a3*b0; acc[3][1]+=a3*b1; acc[3][2]+=a3*b2; acc[3][3]+=a3*b3;
        }
        __syncthreads();
    }
    const int bh = b * NH + h;
    const int n0 = m0 & (NTOK - 1);
    #pragma unroll
    for (int i = 0; i < 4; ++i) {
        float ss = acc[i][0]*acc[i][0] + acc[i][1]*acc[i][1]
                 + acc[i][2]*acc[i][2] + acc[i][3]*acc[i][3];
        #pragma unroll
        for (int msk = 1; msk < 16; msk <<= 1) ss += __shfl_xor(ss, msk, 16);
        float rn = rsqrtf(ss);
        int n = n0 + 4*ty + i;
        ushort4 o;
        o.x = f2bf(acc[i][0]*rn); o.y = f2bf(acc[i][1]*rn);
        o.z = f2bf(acc[i][2]*rn); o.w = f2bf(acc[i][3]*rn);
        *(ushort4*)&vn[((size_t)bh * NTOK + n) * HD + 4*tx] = o;
    }
    ushort (*T)[72] = (ushort (*)[72])smem;
    #pragma unroll
    for (int i = 0; i < 4; ++i)
        #pragma unroll
        for (int j = 0; j < 4; ++j)
            T[4*tx + j][4*ty + i] = f2bf(acc[i][j]);
    __syncthreads();
    {
        int d = tid >> 2, c = tid & 3;
        uint4 lo = *(const uint4*)&T[d][c*16];
        uint4 hi = *(const uint4*)&T[d][c*16 + 8];
        size_t go = ((size_t)bh * HD + d) * NTOK + n0 + c*16;
        *(uint4*)&vt[go]     = lo;
        *(uint4*)&vt[go + 8] = hi;
    }
}

// ---------------------------------------------------------------------------
// Kernel 2: flash attention, 32x32 swapped-operand structure.
// Bounded-logit softmax: Q,K unit vectors => |s|<=~1, p = exp2(s*0.125*log2e),
// no max tracking, no rescale (softmax shift-invariance).
// Double-buffered K/V LDS, ONE barrier per tile. XCD-swizzled 1D grid:
// all 8 q-blocks of a bh share bid%8 -> KV pinned to one XCD L2.
// ---------------------------------------------------------------------------
__global__ __launch_bounds__(256) void attn_kernel(
    const ushort* __restrict__ vn, const ushort* __restrict__ vt,
    float* __restrict__ out)
{
    __shared__ __align__(16) ushort Klds[2][64 * 64];   // [kv][d], swizzled
    __shared__ __align__(16) ushort Vlds[2][64 * 64];   // [d][kv], swizzled
    const int sblk = blockIdx.x;                 // 0..767
    const int tt   = sblk >> 3;
    const int bh   = (sblk & 7) + 8 * (tt >> 3); // XCD(bid%8) == bh%8
    const int q0   = (tt & 7) * 128;
    const int tid = threadIdx.x;
    const int wv  = tid >> 6;
    const int l   = tid & 63;
    const int ql  = l & 31;          // q column (one q-row per lane)
    const int h   = l >> 5;          // half

    const ushort* vb  = vn + (size_t)bh * NTOK * HD;
    const ushort* vtb = vt + (size_t)bh * HD * NTOK;

    // Q B-frags: B[k=d][n=q], lane holds d = 16ks + 8h + j of row q0+wv*32+ql
    short8 qB[4];
    {
        int qrow = q0 + wv * 32 + ql;
        #pragma unroll
        for (int ks = 0; ks < 4; ++ks)
            qB[ks] = *(const short8*)(vb + (size_t)qrow * HD + ks * 16 + h * 8);
    }

    const int sr0 = tid >> 3, sr1 = sr0 + 32;
    const int sc  = tid & 7;
    const int slt = (sc ^ (sr0 & 7)) * 8;        // sr1&7 == sr0&7
    uint4 kreg0, kreg1, vreg0, vreg1;

    f32x16 oT[2] = {};
    float l_acc = 0.f;
    const float CS = 0.18033688f;                 // 0.125 * log2(e)

    // prologue: stage tile 0 into buf 0
    kreg0 = *(const uint4*)(vb + (size_t)sr0 * HD + sc * 8);
    kreg1 = *(const uint4*)(vb + (size_t)sr1 * HD + sc * 8);
    vreg0 = *(const uint4*)(vtb + (size_t)sr0 * NTOK + sc * 8);
    vreg1 = *(const uint4*)(vtb + (size_t)sr1 * NTOK + sc * 8);
    *(uint4*)(&Klds[0][0] + sr0 * 64 + slt) = kreg0;
    *(uint4*)(&Klds[0][0] + sr1 * 64 + slt) = kreg1;
    *(uint4*)(&Vlds[0][0] + sr0 * 64 + slt) = vreg0;
    *(uint4*)(&Vlds[0][0] + sr1 * 64 + slt) = vreg1;
    __syncthreads();

    for (int kt = 0; kt < NTOK / 64; ++kt) {
        const int cur = kt & 1;
        const ushort* Kb = &Klds[cur][0];
        const ushort* Vb = &Vlds[cur][0];

        // T14: issue next tile's global loads early (latency hides under MFMA)
        if (kt < NTOK / 64 - 1) {
            int kb = (kt + 1) * 64;
            kreg0 = *(const uint4*)(vb + (size_t)(kb + sr0) * HD + sc * 8);
            kreg1 = *(const uint4*)(vb + (size_t)(kb + sr1) * HD + sc * 8);
            vreg0 = *(const uint4*)(vtb + (size_t)sr0 * NTOK + kb + sc * 8);
            vreg1 = *(const uint4*)(vtb + (size_t)sr1 * NTOK + kb + sc * 8);
        }

        // S^T = K . Q : st[g] covers kv = 32g + (i&3)+8*(i>>2)+4h, q = ql
        f32x16 st[2] = {};
        __builtin_amdgcn_s_setprio(1);
        #pragma unroll
        for (int ks = 0; ks < 4; ++ks) {
            int so = ((2 * ks + h) ^ (ql & 7)) * 8;
            short8 k0 = *(const short8*)(Kb + ql * 64 + so);
            short8 k1 = *(const short8*)(Kb + (32 + ql) * 64 + so);
            st[0] = mfma32(k0, qB[ks], st[0]);
            st[1] = mfma32(k1, qB[ks], st[1]);
        }
        __builtin_amdgcn_s_setprio(0);

        // bounded softmax: p = exp2(s*CS), no max, no rescale
        #pragma unroll
        for (int g = 0; g < 2; ++g)
            #pragma unroll
            for (int i = 0; i < 16; ++i)
                st[g][i] = __builtin_amdgcn_exp2f(st[g][i] * CS);

        float ts[16];
        #pragma unroll
        for (int i = 0; i < 16; ++i) ts[i] = st[0][i] + st[1][i];
        #pragma unroll
        for (int s = 8; s >= 1; s >>= 1)
            #pragma unroll
            for (int i = 0; i < s; ++i) ts[i] += ts[i + s];
        l_acc += ts[0];

        // pack P to bf16 pairs: pb2[g][t][u] = (p[4t+2u], p[4t+2u+1]) of st[g]
        unsigned pb2[2][4][2];
        #pragma unroll
        for (int g = 0; g < 2; ++g)
            #pragma unroll
            for (int t = 0; t < 4; ++t)
                #pragma unroll
                for (int u = 0; u < 2; ++u)
                    asm("v_cvt_pk_bf16_f32 %0, %1, %2"
                        : "=v"(pb2[g][t][u])
                        : "v"(st[g][4 * t + 2 * u]), "v"(st[g][4 * t + 2 * u + 1]));

        // O^T += V^T . P^T : per 16-kv step s, B-frag built by permlane32_swap
        __builtin_amdgcn_s_setprio(1);
        #pragma unroll
        for (int s = 0; s < 4; ++s) {
            const int g = s >> 1, sp = s & 1;
            unsigned x0 = pb2[g][2 * sp][0], y0 = pb2[g][2 * sp + 1][0];
            unsigned x1 = pb2[g][2 * sp][1], y1 = pb2[g][2 * sp + 1][1];
            asm volatile("v_permlane32_swap_b32 %0, %1" : "+v"(x0), "+v"(y0));
            asm volatile("v_permlane32_swap_b32 %0, %1" : "+v"(x1), "+v"(y1));
            union { unsigned u[4]; short8 s8; } pb;
            pb.u[0] = x0; pb.u[1] = x1; pb.u[2] = y0; pb.u[3] = y1;
            int so = ((2 * s + h) ^ (ql & 7)) * 8;
            short8 v0 = *(const short8*)(Vb + ql * 64 + so);
            short8 v1 = *(const short8*)(Vb + (32 + ql) * 64 + so);
            oT[0] = mfma32(v0, pb.s8, oT[0]);
            oT[1] = mfma32(v1, pb.s8, oT[1]);
        }
        __builtin_amdgcn_s_setprio(0);

        // write next tile into the alternate buffer, ONE barrier per tile
        if (kt < NTOK / 64 - 1) {
            *(uint4*)(&Klds[cur ^ 1][0] + sr0 * 64 + slt) = kreg0;
            *(uint4*)(&Klds[cur ^ 1][0] + sr1 * 64 + slt) = kreg1;
            *(uint4*)(&Vlds[cur ^ 1][0] + sr0 * 64 + slt) = vreg0;
            *(uint4*)(&Vlds[cur ^ 1][0] + sr1 * 64 + slt) = vreg1;
        }
        __syncthreads();
    }

    // epilogue: out[n][b][hh*64+d] = O^T[d][q] / l ; d = 32dm + 8t + 4h + e
    const int b = bh / NH, hh = bh % NH;
    float lsum = l_acc + __shfl_xor(l_acc, 32);
    const float inv = 1.f / lsum;
    int n = q0 + wv * 32 + ql;
    float* orow = out + ((size_t)n * BATCH + b) * DM + hh * HD;
    #pragma unroll
    for (int dm = 0; dm < 2; ++dm)
        #pragma unroll
        for (int t = 0; t < 4; ++t) {
            float4 val = make_float4(oT[dm][4 * t] * inv, oT[dm][4 * t + 1] * inv,
                                     oT[dm][4 * t + 2] * inv, oT[dm][4 * t + 3] * inv);
            *(float4*)(orow + dm * 32 + t * 8 + h * 4) = val;
        }
}

extern "C" void kernel_launch(void* const* d_in, const int* in_sizes, int n_in,
                              void* d_out, int out_size, void* d_ws, size_t ws_size,
                              hipStream_t stream) {
    const float* q = (const float*)d_in[0];   // [1024, 8, 768]
    const float* w = (const float*)d_in[1];   // [768, 768]
    float* out = (float*)d_out;               // [1024, 8, 768]

    const size_t QE = (size_t)NTOK * BATCH * DM;     // 6,291,456
    const size_t WE = (size_t)DM * DM;               //   589,824
    const size_t VE = (size_t)NH * BATCH * NTOK * HD;// 6,291,456

    ushort* vn = (ushort*)d_ws;
    ushort* vt = vn + VE;
    size_t need = (2 * VE + 2 * QE + 2 * WE) * sizeof(ushort);

    if (ws_size >= need) {
        ushort* qh = vt + VE;
        ushort* ql = qh + QE;
        ushort* wh = ql + QE;
        ushort* wl = wh + WE;
        split_q_kernel<<<(QE / 8 + 255) / 256, 256, 0, stream>>>(q, qh, ql);
        split_w_kernel<<<(WE / 8 + 255) / 256, 256, 0, stream>>>(w, wh, wl);
        vproj_mfma_kernel<<<dim3(NH, (BATCH * NTOK) / 64), 256, 0, stream>>>(
            qh, ql, wh, wl, vn, vt);
    } else {
        vproj_fp32_kernel<<<dim3(NH, (BATCH * NTOK) / 64), 256, 0, stream>>>(q, w, vn, vt);
    }
    attn_kernel<<<NTOK / 128 * BATCH * NH, 256, 0, stream>>>(vn, vt, out);
}

// Round 7
// 98.504 us; speedup vs baseline: 7.3721x; 1.0529x over previous
//
#include <hip/hip_runtime.h>
#include <hip/hip_bf16.h>

#define NH    12
#define HD    64
#define NTOK  1024
#define BATCH 8
#define DM    768

typedef short  short8  __attribute__((ext_vector_type(8)));
typedef float  f32x4   __attribute__((ext_vector_type(4)));
typedef float  f32x16  __attribute__((ext_vector_type(16)));
typedef unsigned short ushort8 __attribute__((ext_vector_type(8)));

__device__ __forceinline__ ushort f2bf(float f) {
    union { float f; unsigned u; } x; x.f = f;
    unsigned r = x.u + 0x7FFF + ((x.u >> 16) & 1);   // RNE
    return (ushort)(r >> 16);
}
__device__ __forceinline__ float bf2f(ushort h) {
    union { unsigned u; float f; } x; x.u = ((unsigned)h) << 16;
    return x.f;
}
__device__ __forceinline__ void gl_lds16(const ushort* g, ushort* l) {
    __builtin_amdgcn_global_load_lds(
        (const __attribute__((address_space(1))) unsigned int*)g,
        (__attribute__((address_space(3))) unsigned int*)l, 16, 0, 0);
}
__device__ __forceinline__ f32x16 mfma32(short8 a, short8 b, f32x16 c) {
    return __builtin_amdgcn_mfma_f32_32x32x16_bf16(a, b, c, 0, 0, 0);
}

// ---------------------------------------------------------------------------
// Split kernels: x -> (hi, lo) bf16 with hi = bf16(x), lo = bf16(x - hi).
// q is also transposed [n][b][d] -> [b][n][d] so GEMM tile rows are contiguous.
// ---------------------------------------------------------------------------
__global__ __launch_bounds__(256) void split_q_kernel(
    const float* __restrict__ src, ushort* __restrict__ hi, ushort* __restrict__ lo)
{
    int t = blockIdx.x * 256 + threadIdx.x;       // 786432 threads, 8 elems each
    int dblk = t % 96; int nb = t / 96; int b = nb & 7; int n = nb >> 3;
    const float* s = src + (size_t)t * 8;
    size_t o = ((size_t)(b * 1024 + n) * 96 + dblk) * 8;
    float4 x0 = *(const float4*)s, x1 = *(const float4*)(s + 4);
    float xs[8] = {x0.x, x0.y, x0.z, x0.w, x1.x, x1.y, x1.z, x1.w};
    ushort8 h8, l8;
    #pragma unroll
    for (int j = 0; j < 8; ++j) {
        ushort h = f2bf(xs[j]);
        h8[j] = h;
        l8[j] = f2bf(xs[j] - bf2f(h));
    }
    *(ushort8*)(hi + o) = h8;
    *(ushort8*)(lo + o) = l8;
}

__global__ __launch_bounds__(256) void split_w_kernel(
    const float* __restrict__ src, ushort* __restrict__ hi, ushort* __restrict__ lo)
{
    int t = blockIdx.x * 256 + threadIdx.x;       // 73728 threads
    const float* s = src + (size_t)t * 8;
    float4 x0 = *(const float4*)s, x1 = *(const float4*)(s + 4);
    float xs[8] = {x0.x, x0.y, x0.z, x0.w, x1.x, x1.y, x1.z, x1.w};
    ushort8 h8, l8;
    #pragma unroll
    for (int j = 0; j < 8; ++j) {
        ushort h = f2bf(xs[j]);
        h8[j] = h;
        l8[j] = f2bf(xs[j] - bf2f(h));
    }
    size_t o = (size_t)t * 8;
    *(ushort8*)(hi + o) = h8;
    *(ushort8*)(lo + o) = l8;
}

// ---------------------------------------------------------------------------
// vproj via split-bf16 MFMA: C = Ah.Bh + Ah.Bl + Al.Bh  (fp32 accum).
// 128x128 tile (2 heads), BK=64, 4 waves 2x2 (each 64x64), 32x32x16 MFMA.
// XCD-swizzled 1D grid: each XCD owns 8 row-panels x 6 col-blocks -> A-panel
// and w stay in that XCD's L2. Staging: global_load_lds w16, pre-swizzled
// source + swizzled ds_read. Epilogue: C bounce in LDS [128][132] -> per-row
// per-head norm (in-lane) -> vn (normalized bf16) + vt (V^T bf16).
// ---------------------------------------------------------------------------
__global__ __launch_bounds__(256) void vproj_mfma_kernel(
    const ushort* __restrict__ qh, const ushort* __restrict__ ql,
    const ushort* __restrict__ wh, const ushort* __restrict__ wl,
    ushort* __restrict__ vn, ushort* __restrict__ vt)
{
    __shared__ __align__(16) char smem[128 * 132 * 4];   // 67584 B
    ushort* Ah = (ushort*)smem;                  // [128][64] swizzled
    ushort* Al = (ushort*)(smem + 16384);
    ushort* Bh = (ushort*)(smem + 32768);
    ushort* Bl = (ushort*)(smem + 49152);

    const int bid = blockIdx.x;                  // 0..383
    const int xcd = bid & 7, s = bid >> 3;       // s 0..47
    const int nb  = s % 6, mbl = s / 6;          // nb 0..5, mbl 0..7
    const int mb  = xcd * 8 + mbl;               // 0..63
    const int m0  = mb * 128;
    const int n0  = nb * 128;

    const int tid = threadIdx.x, wv = tid >> 6, l = tid & 63;
    const int ln  = l & 31, half = l >> 5;
    const int wr  = wv >> 1, wc = wv & 1;

    // staging: wave wv owns one 128x64 subtile
    const ushort* gsrc = (wv == 0) ? qh : (wv == 1) ? ql : (wv == 2) ? wh : wl;
    ushort* ltile = (wv == 0) ? Ah : (wv == 1) ? Al : (wv == 2) ? Bh : Bl;
    const int srow0 = (wv < 2) ? m0 : n0;

    f32x16 acc[2][2] = {};

    for (int kt = 0; kt < 12; ++kt) {
        __syncthreads();                          // prev ds_reads done
        #pragma unroll
        for (int p = 0; p < 16; ++p) {
            int chunk = p * 64 + l;               // 0..1023
            int r = chunk >> 3, c = chunk & 7;
            int csrc = c ^ (r & 7);               // inverse-swizzled source
            gl_lds16(gsrc + (size_t)(srow0 + r) * 768 + kt * 64 + csrc * 8,
                     ltile + p * 512);            // linear LDS dest
        }
        __syncthreads();                          // vmcnt(0) drained here

        #pragma unroll
        for (int ks = 0; ks < 4; ++ks) {
            const int cc = ks * 2 + half;         // k-chunk: k = cc*8 + j
            short8 a_h[2], a_l[2], b_h[2], b_l[2];
            #pragma unroll
            for (int mi = 0; mi < 2; ++mi) {
                int ra = wr * 64 + mi * 32 + ln;
                int so = (cc ^ (ra & 7)) * 8;
                a_h[mi] = *(const short8*)(Ah + ra * 64 + so);
                a_l[mi] = *(const short8*)(Al + ra * 64 + so);
                int rb = wc * 64 + mi * 32 + ln;
                int sb = (cc ^ (rb & 7)) * 8;
                b_h[mi] = *(const short8*)(Bh + rb * 64 + sb);
                b_l[mi] = *(const short8*)(Bl + rb * 64 + sb);
            }
            #pragma unroll
            for (int mi = 0; mi < 2; ++mi)
                #pragma unroll
                for (int ni = 0; ni < 2; ++ni) {
                    acc[mi][ni] = mfma32(a_h[mi], b_h[ni], acc[mi][ni]);
                    acc[mi][ni] = mfma32(a_h[mi], b_l[ni], acc[mi][ni]);
                    acc[mi][ni] = mfma32(a_l[mi], b_h[ni], acc[mi][ni]);
                }
        }
    }

    // ---- epilogue: C tile -> LDS [128][132] f32, norms, vn + vt ----
    __syncthreads();
    float* Ct = (float*)smem;
    #pragma unroll
    for (int mi = 0; mi < 2; ++mi)
        #pragma unroll
        for (int ni = 0; ni < 2; ++ni)
            #pragma unroll
            for (int i = 0; i < 16; ++i) {
                int row = wr * 64 + mi * 32 + (i & 3) + 8 * (i >> 2) + 4 * half;
                Ct[row * 132 + wc * 64 + ni * 32 + ln] = acc[mi][ni][i];
            }
    __syncthreads();

    const int b   = mb >> 3;
    const int nr0 = (mb & 7) * 128;
    {   // vn: thread t -> (row r = t>>1, head-half hh = t&1), 64 cols in-lane
        int r = tid >> 1, hh = tid & 1;
        const float* src = Ct + r * 132 + hh * 64;
        float ss = 0.f;
        #pragma unroll
        for (int j = 0; j < 16; ++j) {
            float4 v4 = *(const float4*)(src + j * 4);
            ss += v4.x * v4.x + v4.y * v4.y + v4.z * v4.z + v4.w * v4.w;
        }
        float rn = rsqrtf(ss);
        int bhn = b * NH + nb * 2 + hh;
        ushort* dst = vn + ((size_t)bhn * NTOK + nr0 + r) * HD;
        #pragma unroll
        for (int q8 = 0; q8 < 8; ++q8) {
            float4 u0 = *(const float4*)(src + q8 * 8);
            float4 u1 = *(const float4*)(src + q8 * 8 + 4);
            ushort8 o;
            o[0] = f2bf(u0.x * rn); o[1] = f2bf(u0.y * rn);
            o[2] = f2bf(u0.z * rn); o[3] = f2bf(u0.w * rn);
            o[4] = f2bf(u1.x * rn); o[5] = f2bf(u1.y * rn);
            o[6] = f2bf(u1.z * rn); o[7] = f2bf(u1.w * rn);
            *(ushort8*)(dst + q8 * 8) = o;
        }
    }
    {   // vt: thread t -> (col d = t&127, 64-row segment seg = t>>7)
        int d = tid & 127, seg = tid >> 7;
        int bhn = b * NH + nb * 2 + (d >> 6);
        int dd = d & 63;
        ushort* dst = vt + ((size_t)bhn * HD + dd) * NTOK + nr0 + seg * 64;
        #pragma unroll
        for (int q8 = 0; q8 < 8; ++q8) {
            ushort8 o;
            #pragma unroll
            for (int j = 0; j < 8; ++j)
                o[j] = f2bf(Ct[(seg * 64 + q8 * 8 + j) * 132 + d]);
            *(ushort8*)(dst + q8 * 8) = o;
        }
    }
}

// ---------------------------------------------------------------------------
// Fallback fp32 vproj (used only if ws_size can't hold the split arrays).
// ---------------------------------------------------------------------------
__global__ __launch_bounds__(256) void vproj_fp32_kernel(
    const float* __restrict__ q, const float* __restrict__ w,
    ushort* __restrict__ vn, ushort* __restrict__ vt)
{
    __shared__ __align__(16) char smem[2 * 32 * 65 * 4];
    float (*As)[65] = (float (*)[65])smem;
    float (*Bs)[65] = (float (*)[65])(smem + 32 * 65 * 4);
    const int h = blockIdx.x, mb = blockIdx.y;
    const int tid = threadIdx.x;
    const int tx = tid & 15, ty = tid >> 4;
    const int m0 = mb * 64, b = m0 >> 10;
    const int lk = tid & 31, lr = tid >> 5;
    float acc[4][4] = {};
    for (int kt = 0; kt < DM; kt += 32) {
        #pragma unroll
        for (int p = 0; p < 8; ++p) {
            int row = lr + p * 8;
            int n = (m0 + row) & (NTOK - 1);
            As[lk][row] = q[(size_t)(n * BATCH + b) * DM + kt + lk];
            Bs[lk][row] = w[(size_t)(h * HD + row) * DM + kt + lk];
        }
        __syncthreads();
        #pragma unroll 8
        for (int k = 0; k < 32; ++k) {
            float a0 = As[k][4*ty+0], a1 = As[k][4*ty+1];
            float a2 = As[k][4*ty+2], a3 = As[k][4*ty+3];
            float b0 = Bs[k][4*tx+0], b1 = Bs[k][4*tx+1];
            float b2 = Bs[k][4*tx+2], b3 = Bs[k][4*tx+3];
            acc[0][0]+=a0*b0; acc[0][1]+=a0*b1; acc[0][2]+=a0*b2; acc[0][3]+=a0*b3;
            acc[1][0]+=a1*b0; acc[1][1]+=a1*b1; acc[1][2]+=a1*b2; acc[1][3]+=a1*b3;
            acc[2][0]+=a2*b0; acc[2][1]+=a2*b1; acc[2][2]+=a2*b2; acc[2][3]+=a2*b3;
            acc[3][0]+=a3*b0; acc[3][1]+=a3*b1; acc[3][2]+=a3*b2; acc[3][3]+=a3*b3;
        }
        __syncthreads();
    }
    const int bh = b * NH + h;
    const int n0 = m0 & (NTOK - 1);
    #pragma unroll
    for (int i = 0; i < 4; ++i) {
        float ss = acc[i][0]*acc[i][0] + acc[i][1]*acc[i][1]
                 + acc[i][2]*acc[i][2] + acc[i][3]*acc[i][3];
        #pragma unroll
        for (int msk = 1; msk < 16; msk <<= 1) ss += __shfl_xor(ss, msk, 16);
        float rn = rsqrtf(ss);
        int n = n0 + 4*ty + i;
        ushort4 o;
        o.x = f2bf(acc[i][0]*rn); o.y = f2bf(acc[i][1]*rn);
        o.z = f2bf(acc[i][2]*rn); o.w = f2bf(acc[i][3]*rn);
        *(ushort4*)&vn[((size_t)bh * NTOK + n) * HD + 4*tx] = o;
    }
    ushort (*T)[72] = (ushort (*)[72])smem;
    #pragma unroll
    for (int i = 0; i < 4; ++i)
        #pragma unroll
        for (int j = 0; j < 4; ++j)
            T[4*tx + j][4*ty + i] = f2bf(acc[i][j]);
    __syncthreads();
    {
        int d = tid >> 2, c = tid & 3;
        uint4 lo = *(const uint4*)&T[d][c*16];
        uint4 hi = *(const uint4*)&T[d][c*16 + 8];
        size_t go = ((size_t)bh * HD + d) * NTOK + n0 + c*16;
        *(uint4*)&vt[go]     = lo;
        *(uint4*)&vt[go + 8] = hi;
    }
}

// ---------------------------------------------------------------------------
// Kernel 2: flash attention, 32x32 swapped-operand structure. (unchanged)
// Bounded-logit softmax: Q,K unit vectors => |s|<=~1, p = exp2(s*0.125*log2e),
// no max tracking, no rescale. Double-buffered K/V LDS, ONE barrier per tile.
// XCD-swizzled grid: all 8 q-blocks of a bh share bid%8.
// ---------------------------------------------------------------------------
__global__ __launch_bounds__(256) void attn_kernel(
    const ushort* __restrict__ vn, const ushort* __restrict__ vt,
    float* __restrict__ out)
{
    __shared__ __align__(16) ushort Klds[2][64 * 64];   // [kv][d], swizzled
    __shared__ __align__(16) ushort Vlds[2][64 * 64];   // [d][kv], swizzled
    const int sblk = blockIdx.x;                 // 0..767
    const int tt   = sblk >> 3;
    const int bh   = (sblk & 7) + 8 * (tt >> 3); // XCD(bid%8) == bh%8
    const int q0   = (tt & 7) * 128;
    const int tid = threadIdx.x;
    const int wv  = tid >> 6;
    const int l   = tid & 63;
    const int ql  = l & 31;          // q column (one q-row per lane)
    const int h   = l >> 5;          // half

    const ushort* vb  = vn + (size_t)bh * NTOK * HD;
    const ushort* vtb = vt + (size_t)bh * HD * NTOK;

    short8 qB[4];
    {
        int qrow = q0 + wv * 32 + ql;
        #pragma unroll
        for (int ks = 0; ks < 4; ++ks)
            qB[ks] = *(const short8*)(vb + (size_t)qrow * HD + ks * 16 + h * 8);
    }

    const int sr0 = tid >> 3, sr1 = sr0 + 32;
    const int sc  = tid & 7;
    const int slt = (sc ^ (sr0 & 7)) * 8;        // sr1&7 == sr0&7
    uint4 kreg0, kreg1, vreg0, vreg1;

    f32x16 oT[2] = {};
    float l_acc = 0.f;
    const float CS = 0.18033688f;                 // 0.125 * log2(e)

    kreg0 = *(const uint4*)(vb + (size_t)sr0 * HD + sc * 8);
    kreg1 = *(const uint4*)(vb + (size_t)sr1 * HD + sc * 8);
    vreg0 = *(const uint4*)(vtb + (size_t)sr0 * NTOK + sc * 8);
    vreg1 = *(const uint4*)(vtb + (size_t)sr1 * NTOK + sc * 8);
    *(uint4*)(&Klds[0][0] + sr0 * 64 + slt) = kreg0;
    *(uint4*)(&Klds[0][0] + sr1 * 64 + slt) = kreg1;
    *(uint4*)(&Vlds[0][0] + sr0 * 64 + slt) = vreg0;
    *(uint4*)(&Vlds[0][0] + sr1 * 64 + slt) = vreg1;
    __syncthreads();

    for (int kt = 0; kt < NTOK / 64; ++kt) {
        const int cur = kt & 1;
        const ushort* Kb = &Klds[cur][0];
        const ushort* Vb = &Vlds[cur][0];

        if (kt < NTOK / 64 - 1) {
            int kb = (kt + 1) * 64;
            kreg0 = *(const uint4*)(vb + (size_t)(kb + sr0) * HD + sc * 8);
            kreg1 = *(const uint4*)(vb + (size_t)(kb + sr1) * HD + sc * 8);
            vreg0 = *(const uint4*)(vtb + (size_t)sr0 * NTOK + kb + sc * 8);
            vreg1 = *(const uint4*)(vtb + (size_t)sr1 * NTOK + kb + sc * 8);
        }

        f32x16 st[2] = {};
        __builtin_amdgcn_s_setprio(1);
        #pragma unroll
        for (int ks = 0; ks < 4; ++ks) {
            int so = ((2 * ks + h) ^ (ql & 7)) * 8;
            short8 k0 = *(const short8*)(Kb + ql * 64 + so);
            short8 k1 = *(const short8*)(Kb + (32 + ql) * 64 + so);
            st[0] = mfma32(k0, qB[ks], st[0]);
            st[1] = mfma32(k1, qB[ks], st[1]);
        }
        __builtin_amdgcn_s_setprio(0);

        #pragma unroll
        for (int g = 0; g < 2; ++g)
            #pragma unroll
            for (int i = 0; i < 16; ++i)
                st[g][i] = __builtin_amdgcn_exp2f(st[g][i] * CS);

        float ts[16];
        #pragma unroll
        for (int i = 0; i < 16; ++i) ts[i] = st[0][i] + st[1][i];
        #pragma unroll
        for (int s = 8; s >= 1; s >>= 1)
            #pragma unroll
            for (int i = 0; i < s; ++i) ts[i] += ts[i + s];
        l_acc += ts[0];

        unsigned pb2[2][4][2];
        #pragma unroll
        for (int g = 0; g < 2; ++g)
            #pragma unroll
            for (int t = 0; t < 4; ++t)
                #pragma unroll
                for (int u = 0; u < 2; ++u)
                    asm("v_cvt_pk_bf16_f32 %0, %1, %2"
                        : "=v"(pb2[g][t][u])
                        : "v"(st[g][4 * t + 2 * u]), "v"(st[g][4 * t + 2 * u + 1]));

        __builtin_amdgcn_s_setprio(1);
        #pragma unroll
        for (int s = 0; s < 4; ++s) {
            const int g = s >> 1, sp = s & 1;
            unsigned x0 = pb2[g][2 * sp][0], y0 = pb2[g][2 * sp + 1][0];
            unsigned x1 = pb2[g][2 * sp][1], y1 = pb2[g][2 * sp + 1][1];
            asm volatile("v_permlane32_swap_b32 %0, %1" : "+v"(x0), "+v"(y0));
            asm volatile("v_permlane32_swap_b32 %0, %1" : "+v"(x1), "+v"(y1));
            union { unsigned u[4]; short8 s8; } pb;
            pb.u[0] = x0; pb.u[1] = x1; pb.u[2] = y0; pb.u[3] = y1;
            int so = ((2 * s + h) ^ (ql & 7)) * 8;
            short8 v0 = *(const short8*)(Vb + ql * 64 + so);
            short8 v1 = *(const short8*)(Vb + (32 + ql) * 64 + so);
            oT[0] = mfma32(v0, pb.s8, oT[0]);
            oT[1] = mfma32(v1, pb.s8, oT[1]);
        }
        __builtin_amdgcn_s_setprio(0);

        if (kt < NTOK / 64 - 1) {
            *(uint4*)(&Klds[cur ^ 1][0] + sr0 * 64 + slt) = kreg0;
            *(uint4*)(&Klds[cur ^ 1][0] + sr1 * 64 + slt) = kreg1;
            *(uint4*)(&Vlds[cur ^ 1][0] + sr0 * 64 + slt) = vreg0;
            *(uint4*)(&Vlds[cur ^ 1][0] + sr1 * 64 + slt) = vreg1;
        }
        __syncthreads();
    }

    const int b = bh / NH, hh = bh % NH;
    float lsum = l_acc + __shfl_xor(l_acc, 32);
    const float inv = 1.f / lsum;
    int n = q0 + wv * 32 + ql;
    float* orow = out + ((size_t)n * BATCH + b) * DM + hh * HD;
    #pragma unroll
    for (int dm = 0; dm < 2; ++dm)
        #pragma unroll
        for (int t = 0; t < 4; ++t) {
            float4 val = make_float4(oT[dm][4 * t] * inv, oT[dm][4 * t + 1] * inv,
                                     oT[dm][4 * t + 2] * inv, oT[dm][4 * t + 3] * inv);
            *(float4*)(orow + dm * 32 + t * 8 + h * 4) = val;
        }
}

extern "C" void kernel_launch(void* const* d_in, const int* in_sizes, int n_in,
                              void* d_out, int out_size, void* d_ws, size_t ws_size,
                              hipStream_t stream) {
    const float* q = (const float*)d_in[0];   // [1024, 8, 768]
    const float* w = (const float*)d_in[1];   // [768, 768]
    float* out = (float*)d_out;               // [1024, 8, 768]

    const size_t QE = (size_t)NTOK * BATCH * DM;     // 6,291,456
    const size_t WE = (size_t)DM * DM;               //   589,824
    const size_t VE = (size_t)NH * BATCH * NTOK * HD;// 6,291,456

    ushort* vn = (ushort*)d_ws;
    ushort* vt = vn + VE;
    size_t need = (2 * VE + 2 * QE + 2 * WE) * sizeof(ushort);

    if (ws_size >= need) {
        ushort* qh = vt + VE;
        ushort* ql = qh + QE;
        ushort* wh = ql + QE;
        ushort* wl = wh + WE;
        split_q_kernel<<<(QE / 8 + 255) / 256, 256, 0, stream>>>(q, qh, ql);
        split_w_kernel<<<(WE / 8 + 255) / 256, 256, 0, stream>>>(w, wh, wl);
        vproj_mfma_kernel<<<384, 256, 0, stream>>>(qh, ql, wh, wl, vn, vt);
    } else {
        vproj_fp32_kernel<<<dim3(NH, (BATCH * NTOK) / 64), 256, 0, stream>>>(q, w, vn, vt);
    }
    attn_kernel<<<NTOK / 128 * BATCH * NH, 256, 0, stream>>>(vn, vt, out);
}